// Round 1
// baseline (3119.523 us; speedup 1.0000x reference)
//
#include <hip/hip_runtime.h>
#include <math.h>

// Problem constants (B=2, S=2048, D=1024, H=16, HD=64, FF=4096)
#define DD   1024
#define HH   16
#define HDD  64
#define FFF  4096
#define NB   2
#define NS   2048
#define NR   (NB * NS)     // 4096 rows
#define TDQ  (3 * DD)      // 3072

__device__ __forceinline__ float4 ld4(const float* p) {
    return *reinterpret_cast<const float4*>(p);
}

__device__ __forceinline__ float gelu_f(float x) {
    return 0.5f * x * (1.0f + erff(x * 0.70710678118654752440f));
}

// ---------------- LayerNorm: one block per row, 256 threads, one float4 each
__global__ __launch_bounds__(256) void ln_kernel(const float* __restrict__ in,
        const float* __restrict__ gw, const float* __restrict__ bw,
        float* __restrict__ out) {
    int row = blockIdx.x;
    float4 v = reinterpret_cast<const float4*>(in + (size_t)row * DD)[threadIdx.x];
    float s1 = v.x + v.y + v.z + v.w;
    float s2 = v.x * v.x + v.y * v.y + v.z * v.z + v.w * v.w;
#pragma unroll
    for (int off = 1; off < 64; off <<= 1) {
        s1 += __shfl_xor(s1, off);
        s2 += __shfl_xor(s2, off);
    }
    __shared__ float r1[4], r2[4];
    int wid = threadIdx.x >> 6;
    if ((threadIdx.x & 63) == 0) { r1[wid] = s1; r2[wid] = s2; }
    __syncthreads();
    s1 = r1[0] + r1[1] + r1[2] + r1[3];
    s2 = r2[0] + r2[1] + r2[2] + r2[3];
    float mu   = s1 * (1.0f / DD);
    float var  = s2 * (1.0f / DD) - mu * mu;
    float rstd = rsqrtf(var + 1e-5f);
    float4 g = reinterpret_cast<const float4*>(gw)[threadIdx.x];
    float4 b = reinterpret_cast<const float4*>(bw)[threadIdx.x];
    float4 o;
    o.x = (v.x - mu) * rstd * g.x + b.x;
    o.y = (v.y - mu) * rstd * g.y + b.y;
    o.z = (v.z - mu) * rstd * g.z + b.z;
    o.w = (v.w - mu) * rstd * g.w + b.w;
    reinterpret_cast<float4*>(out + (size_t)row * DD)[threadIdx.x] = o;
}

// ---------------- fp32 tiled GEMM: 128x128 tile, BK=16, 256 thr, 8x8/thread
// EPI: 0 = +bias, 1 = +bias +resid, 2 = +bias then exact GELU
template<int EPI>
__global__ __launch_bounds__(256) void gemm_kernel(
        const float* __restrict__ A, const float* __restrict__ Bm,
        const float* __restrict__ bias, const float* __restrict__ resid,
        float* __restrict__ C, int M, int N, int K) {
    __shared__ float As[16][132];   // k-major (transposed), +4 pad
    __shared__ float Bs[16][132];
    const int tid = threadIdx.x;
    const int ty = tid >> 4, tx = tid & 15;
    const int m0 = blockIdx.y * 128, n0 = blockIdx.x * 128;

    float acc[8][8];
#pragma unroll
    for (int i = 0; i < 8; ++i)
#pragma unroll
        for (int j = 0; j < 8; ++j) acc[i][j] = 0.0f;

    const int ar  = tid >> 2;          // 0..63
    const int ak  = (tid & 3) << 2;    // 0,4,8,12
    const int bkr = tid >> 5;          // 0..7
    const int bc  = (tid & 31) << 2;   // 0..124
    const float* Ap0 = A + (size_t)(m0 + ar) * K + ak;
    const float* Ap1 = Ap0 + (size_t)64 * K;
    const float* Bp0 = Bm + (size_t)bkr * N + n0 + bc;
    const float* Bp1 = Bp0 + (size_t)8 * N;

    for (int k0 = 0; k0 < K; k0 += 16) {
        float4 a0 = ld4(Ap0 + k0);
        float4 a1 = ld4(Ap1 + k0);
        float4 b0 = ld4(Bp0 + (size_t)k0 * N);
        float4 b1 = ld4(Bp1 + (size_t)k0 * N);
        __syncthreads();
        As[ak + 0][ar] = a0.x; As[ak + 1][ar] = a0.y;
        As[ak + 2][ar] = a0.z; As[ak + 3][ar] = a0.w;
        As[ak + 0][64 + ar] = a1.x; As[ak + 1][64 + ar] = a1.y;
        As[ak + 2][64 + ar] = a1.z; As[ak + 3][64 + ar] = a1.w;
        *reinterpret_cast<float4*>(&Bs[bkr][bc])     = b0;
        *reinterpret_cast<float4*>(&Bs[bkr + 8][bc]) = b1;
        __syncthreads();
#pragma unroll
        for (int k = 0; k < 16; ++k) {
            float ax[8], by[8];
            float4 t;
            t = ld4(&As[k][4 * ty]);      ax[0] = t.x; ax[1] = t.y; ax[2] = t.z; ax[3] = t.w;
            t = ld4(&As[k][64 + 4 * ty]); ax[4] = t.x; ax[5] = t.y; ax[6] = t.z; ax[7] = t.w;
            t = ld4(&Bs[k][4 * tx]);      by[0] = t.x; by[1] = t.y; by[2] = t.z; by[3] = t.w;
            t = ld4(&Bs[k][64 + 4 * tx]); by[4] = t.x; by[5] = t.y; by[6] = t.z; by[7] = t.w;
#pragma unroll
            for (int i = 0; i < 8; ++i)
#pragma unroll
                for (int j = 0; j < 8; ++j)
                    acc[i][j] = fmaf(ax[i], by[j], acc[i][j]);
        }
    }
    // epilogue
#pragma unroll
    for (int ih = 0; ih < 2; ++ih)
#pragma unroll
        for (int i = 0; i < 4; ++i) {
            int r = m0 + ih * 64 + 4 * ty + i;
#pragma unroll
            for (int jh = 0; jh < 2; ++jh) {
                int c = n0 + jh * 64 + 4 * tx;
                float4 bv = ld4(bias + c);
                float4 o;
                o.x = acc[ih * 4 + i][jh * 4 + 0] + bv.x;
                o.y = acc[ih * 4 + i][jh * 4 + 1] + bv.y;
                o.z = acc[ih * 4 + i][jh * 4 + 2] + bv.z;
                o.w = acc[ih * 4 + i][jh * 4 + 3] + bv.w;
                if (EPI == 1) {
                    float4 rv = ld4(resid + (size_t)r * N + c);
                    o.x += rv.x; o.y += rv.y; o.z += rv.z; o.w += rv.w;
                }
                if (EPI == 2) {
                    o.x = gelu_f(o.x); o.y = gelu_f(o.y);
                    o.z = gelu_f(o.z); o.w = gelu_f(o.w);
                }
                *reinterpret_cast<float4*>(C + (size_t)r * N + c) = o;
            }
        }
}

// ---------------- RoPE on q,k inside qkv (layout: row-major [N][h*192 + {q|k|v}*64 + d])
__global__ __launch_bounds__(256) void rope_kernel(float* __restrict__ qkv,
        const float* __restrict__ sp) {
    int row = blockIdx.x;
    int s = row & (NS - 1);
    __shared__ float cs[HDD], sn[HDD];
    if (threadIdx.x < HDD) {
        float v = sp[(size_t)s * HDD + threadIdx.x];
        cs[threadIdx.x] = cosf(v);
        sn[threadIdx.x] = sinf(v);
    }
    __syncthreads();
    float* base = qkv + (size_t)row * TDQ;
    for (int it = threadIdx.x; it < HH * 2 * 32; it += 256) {
        int d  = it & 31;
        int qk = (it >> 5) & 1;
        int h  = it >> 6;
        float* p = base + h * 192 + qk * 64;
        float x0 = p[d], x1 = p[d + 32];
        p[d]      = x0 * cs[d]      - x1 * sn[d];      // rot = -x[d+32]
        p[d + 32] = x1 * cs[d + 32] + x0 * sn[d + 32]; // rot =  x[d-32]
    }
}

// ---------------- Flash attention, fp32. 64-row Q tile, 64-col K tiles, online softmax.
// Thread (ty,tx): rows 4*ty+i, cols tx+16*j (strided cols -> 2-way LDS banks on float4)
__global__ __launch_bounds__(256) void attn_kernel(const float* __restrict__ qkv,
        const float* __restrict__ pos_bias, const int* __restrict__ mask,
        float* __restrict__ vals) {
    __shared__ float Qs[64][68];
    __shared__ float Ks[64][68];
    __shared__ float Vts[64][68];   // transposed: Vts[d][kvrow]
    __shared__ float Ps[64][68];
    const int tid = threadIdx.x;
    const int ty = tid >> 4, tx = tid & 15;
    const int qt = blockIdx.x, bh = blockIdx.y;
    const int b = bh >> 4, h = bh & 15;
    const int q0 = qt * 64;

#pragma unroll
    for (int it = 0; it < 4; ++it) {
        int r = it * 16 + ty;
        float4 v = ld4(qkv + (size_t)(b * NS + q0 + r) * TDQ + h * 192 + 4 * tx);
        *reinterpret_cast<float4*>(&Qs[r][4 * tx]) = v;
    }
    float o[4][4], m[4], l[4];
#pragma unroll
    for (int i = 0; i < 4; ++i) {
        m[i] = -INFINITY; l[i] = 0.0f;
#pragma unroll
        for (int j = 0; j < 4; ++j) o[i][j] = 0.0f;
    }
    __syncthreads();

    for (int kt = 0; kt < NS / 64; ++kt) {
        float4 kv[4], vv[4];
#pragma unroll
        for (int it = 0; it < 4; ++it) {
            int r = it * 16 + ty;
            const float* src = qkv + (size_t)(b * NS + kt * 64 + r) * TDQ + h * 192;
            kv[it] = ld4(src + 64  + 4 * tx);
            vv[it] = ld4(src + 128 + 4 * tx);
        }
        __syncthreads();   // prior iter's LDS reads complete
#pragma unroll
        for (int it = 0; it < 4; ++it) {
            int r = it * 16 + ty;
            *reinterpret_cast<float4*>(&Ks[r][4 * tx]) = kv[it];
            Vts[4 * tx + 0][r] = vv[it].x;
            Vts[4 * tx + 1][r] = vv[it].y;
            Vts[4 * tx + 2][r] = vv[it].z;
            Vts[4 * tx + 3][r] = vv[it].w;
        }
        __syncthreads();

        // S = Q K^T
        float sv[4][4];
#pragma unroll
        for (int i = 0; i < 4; ++i)
#pragma unroll
            for (int j = 0; j < 4; ++j) sv[i][j] = 0.0f;
#pragma unroll
        for (int d4 = 0; d4 < 16; ++d4) {
            float4 kf[4];
#pragma unroll
            for (int j = 0; j < 4; ++j) kf[j] = ld4(&Ks[tx + 16 * j][4 * d4]);
#pragma unroll
            for (int i = 0; i < 4; ++i) {
                float4 qf = ld4(&Qs[4 * ty + i][4 * d4]);
#pragma unroll
                for (int j = 0; j < 4; ++j)
                    sv[i][j] += qf.x * kf[j].x + qf.y * kf[j].y
                              + qf.z * kf[j].z + qf.w * kf[j].w;
            }
        }
        // bias, scale, mask (reference order: (s+bias)/8 then mask==0 -> NEG)
#pragma unroll
        for (int i = 0; i < 4; ++i) {
            int gr = q0 + 4 * ty + i;
#pragma unroll
            for (int j = 0; j < 4; ++j) {
                int gc = kt * 64 + tx + 16 * j;
                float bb = pos_bias[((size_t)h * NS + gr) * NS + gc];
                int   mm = mask[(size_t)gr * NS + gc];
                float sc = (sv[i][j] + bb) * 0.125f;
                sv[i][j] = (mm == 0) ? -9.0e15f : sc;
            }
        }
        // online softmax
#pragma unroll
        for (int i = 0; i < 4; ++i) {
            float mloc = fmaxf(fmaxf(sv[i][0], sv[i][1]), fmaxf(sv[i][2], sv[i][3]));
#pragma unroll
            for (int off = 1; off < 16; off <<= 1)
                mloc = fmaxf(mloc, __shfl_xor(mloc, off));
            float mnew = fmaxf(m[i], mloc);
            float corr = __expf(m[i] - mnew);
            float ps = 0.0f;
#pragma unroll
            for (int j = 0; j < 4; ++j) {
                float p = __expf(sv[i][j] - mnew);
                Ps[4 * ty + i][tx + 16 * j] = p;
                ps += p;
            }
#pragma unroll
            for (int off = 1; off < 16; off <<= 1)
                ps += __shfl_xor(ps, off);
            l[i] = l[i] * corr + ps;
            m[i] = mnew;
#pragma unroll
            for (int j = 0; j < 4; ++j) o[i][j] *= corr;
        }
        __syncthreads();   // Ps visible
        // O += P V
#pragma unroll
        for (int k4 = 0; k4 < 16; ++k4) {
            float4 vf[4];
#pragma unroll
            for (int j = 0; j < 4; ++j) vf[j] = ld4(&Vts[tx + 16 * j][4 * k4]);
#pragma unroll
            for (int i = 0; i < 4; ++i) {
                float4 pf = ld4(&Ps[4 * ty + i][4 * k4]);
#pragma unroll
                for (int j = 0; j < 4; ++j)
                    o[i][j] += pf.x * vf[j].x + pf.y * vf[j].y
                             + pf.z * vf[j].z + pf.w * vf[j].w;
            }
        }
    }
    // write vals in (b, s, h*64 + d) layout
#pragma unroll
    for (int i = 0; i < 4; ++i) {
        float inv = 1.0f / l[i];
        int gr = b * NS + q0 + 4 * ty + i;
#pragma unroll
        for (int j = 0; j < 4; ++j)
            vals[(size_t)gr * DD + h * HDD + tx + 16 * j] = o[i][j] * inv;
    }
}

extern "C" void kernel_launch(void* const* d_in, const int* in_sizes, int n_in,
                              void* d_out, int out_size, void* d_ws, size_t ws_size,
                              hipStream_t stream) {
    const float* x        = (const float*)d_in[0];
    const int*   mask     = (const int*)d_in[1];
    const float* pos_bias = (const float*)d_in[2];
    const float* sp       = (const float*)d_in[3];
    const float* Wqkv     = (const float*)d_in[4];
    const float* bqkv     = (const float*)d_in[5];
    const float* Wo       = (const float*)d_in[6];
    const float* bo       = (const float*)d_in[7];
    const float* W1       = (const float*)d_in[8];
    const float* b1       = (const float*)d_in[9];
    const float* W2       = (const float*)d_in[10];
    const float* b2       = (const float*)d_in[11];
    const float* g1       = (const float*)d_in[12];
    const float* be1      = (const float*)d_in[13];
    const float* g2       = (const float*)d_in[14];
    const float* be2      = (const float*)d_in[15];
    float* out = (float*)d_out;
    float* ws  = (float*)d_ws;

    // ws layout (floats): [0,4M) xn/x1/x2 ; [4M,16M) qkv ; [16M,20M) vals
    // h (16M floats) reuses [4M,20M) after qkv+vals are dead. Total 80 MB.
    float* xbuf = ws;
    float* qkv  = ws + (size_t)4  * 1048576;
    float* valb = ws + (size_t)16 * 1048576;
    float* hbuf = ws + (size_t)4  * 1048576;

    // 1. xn = LN1(x)
    ln_kernel<<<NR, 256, 0, stream>>>(x, g1, be1, xbuf);
    // 2. qkv = xn @ Wqkv + bqkv
    gemm_kernel<0><<<dim3(TDQ / 128, NR / 128), 256, 0, stream>>>(
        xbuf, Wqkv, bqkv, nullptr, qkv, NR, TDQ, DD);
    // 3. RoPE(q, k) in place
    rope_kernel<<<NR, 256, 0, stream>>>(qkv, sp);
    // 4. vals = attention(q, k, v)
    attn_kernel<<<dim3(NS / 64, NB * HH), 256, 0, stream>>>(qkv, pos_bias, mask, valb);
    // 5. x1 = xn + vals @ Wo + bo   (in-place over xbuf; resid read == write index)
    gemm_kernel<1><<<dim3(DD / 128, NR / 128), 256, 0, stream>>>(
        valb, Wo, bo, xbuf, xbuf, NR, DD, DD);
    // 6. x2 = LN2(x1) in place
    ln_kernel<<<NR, 256, 0, stream>>>(xbuf, g2, be2, xbuf);
    // 7. h = gelu(x2 @ W1 + b1)
    gemm_kernel<2><<<dim3(FFF / 128, NR / 128), 256, 0, stream>>>(
        xbuf, W1, b1, nullptr, hbuf, NR, FFF, DD);
    // 8. out = x2 + h @ W2 + b2
    gemm_kernel<1><<<dim3(DD / 128, NR / 128), 256, 0, stream>>>(
        hbuf, W2, b2, xbuf, out, NR, DD, FFF);
}

// Round 2
// 771.995 us; speedup vs baseline: 4.0409x; 4.0409x over previous
//
#include <hip/hip_runtime.h>
#include <math.h>

// Problem constants (B=2, S=2048, D=1024, H=16, HD=64, FF=4096)
#define DD   1024
#define HH   16
#define HDD  64
#define FFF  4096
#define NB   2
#define NS   2048
#define NR   (NB * NS)     // 4096 rows
#define TDQ  (3 * DD)      // 3072

typedef __attribute__((ext_vector_type(8))) short bfrag;          // 8 bf16 (MFMA A/B operand)
typedef __attribute__((ext_vector_type(4))) float f32x4;          // MFMA C/D
typedef __attribute__((ext_vector_type(8))) unsigned short us8;   // 16B staging chunk
typedef __attribute__((ext_vector_type(4))) unsigned short us4;

__device__ __forceinline__ float4 ld4(const float* p) {
    return *reinterpret_cast<const float4*>(p);
}
__device__ __forceinline__ unsigned short f2bf(float x) {   // round-to-nearest-even bf16
    unsigned int u = __float_as_uint(x);
    u += 0x7fffu + ((u >> 16) & 1u);
    return (unsigned short)(u >> 16);
}
__device__ __forceinline__ float bf2f(unsigned short h) {
    return __uint_as_float(((unsigned int)h) << 16);
}
__device__ __forceinline__ void splitbf(float x, unsigned short& hi, unsigned short& lo) {
    hi = f2bf(x);
    lo = f2bf(x - bf2f(hi));
}
__device__ __forceinline__ float gelu_f(float x) {
    return 0.5f * x * (1.0f + erff(x * 0.70710678118654752440f));
}
#define MFMA(a, b, c) __builtin_amdgcn_mfma_f32_16x16x32_bf16((a), (b), (c), 0, 0, 0)

// ---------------- LayerNorm: fp32 out + hi/lo bf16 planes
__global__ __launch_bounds__(256) void ln_kernel(const float* __restrict__ in,
        const float* __restrict__ gw, const float* __restrict__ bw,
        float* __restrict__ outf, unsigned short* __restrict__ oh,
        unsigned short* __restrict__ ol) {
    int row = blockIdx.x;
    float4 v = reinterpret_cast<const float4*>(in + (size_t)row * DD)[threadIdx.x];
    float s1 = v.x + v.y + v.z + v.w;
    float s2 = v.x * v.x + v.y * v.y + v.z * v.z + v.w * v.w;
#pragma unroll
    for (int off = 1; off < 64; off <<= 1) {
        s1 += __shfl_xor(s1, off);
        s2 += __shfl_xor(s2, off);
    }
    __shared__ float r1[4], r2[4];
    int wid = threadIdx.x >> 6;
    if ((threadIdx.x & 63) == 0) { r1[wid] = s1; r2[wid] = s2; }
    __syncthreads();
    s1 = r1[0] + r1[1] + r1[2] + r1[3];
    s2 = r2[0] + r2[1] + r2[2] + r2[3];
    float mu   = s1 * (1.0f / DD);
    float var  = s2 * (1.0f / DD) - mu * mu;
    float rstd = rsqrtf(var + 1e-5f);
    float4 g = reinterpret_cast<const float4*>(gw)[threadIdx.x];
    float4 b = reinterpret_cast<const float4*>(bw)[threadIdx.x];
    float o[4];
    o[0] = (v.x - mu) * rstd * g.x + b.x;
    o[1] = (v.y - mu) * rstd * g.y + b.y;
    o[2] = (v.z - mu) * rstd * g.z + b.z;
    o[3] = (v.w - mu) * rstd * g.w + b.w;
    float4 of; of.x = o[0]; of.y = o[1]; of.z = o[2]; of.w = o[3];
    reinterpret_cast<float4*>(outf + (size_t)row * DD)[threadIdx.x] = of;
    us4 h4, l4;
#pragma unroll
    for (int j = 0; j < 4; ++j) { unsigned short hh, ll; splitbf(o[j], hh, ll); h4[j] = hh; l4[j] = ll; }
    *reinterpret_cast<us4*>(oh + (size_t)row * DD + threadIdx.x * 4) = h4;
    *reinterpret_cast<us4*>(ol + (size_t)row * DD + threadIdx.x * 4) = l4;
}

// ---------------- Weight transpose+split: W[K][N] fp32 -> Th/Tl[N][K] bf16
__global__ __launch_bounds__(256) void wt_convert(const float* __restrict__ W,
        unsigned short* __restrict__ Th, unsigned short* __restrict__ Tl, int K, int N) {
    __shared__ float s[32][33];
    int tx = threadIdx.x & 31, ty = threadIdx.x >> 5;   // ty 0..7
    int n0 = blockIdx.x * 32, k0 = blockIdx.y * 32;
#pragma unroll
    for (int i = 0; i < 4; ++i)
        s[ty + i * 8][tx] = W[(size_t)(k0 + ty + i * 8) * N + n0 + tx];
    __syncthreads();
#pragma unroll
    for (int i = 0; i < 4; ++i) {
        int n = n0 + ty + i * 8;
        float v = s[tx][ty + i * 8];
        unsigned short h, l; splitbf(v, h, l);
        Th[(size_t)n * K + k0 + tx] = h;
        Tl[(size_t)n * K + k0 + tx] = l;
    }
}

// ---------------- cos/sin tables for RoPE: [S][HD]
__global__ __launch_bounds__(256) void cs_table(const float* __restrict__ sp,
        float* __restrict__ ct, float* __restrict__ st) {
    int i = blockIdx.x * 256 + threadIdx.x;   // NS*HDD total
    float v = sp[i];
    ct[i] = cosf(v);
    st[i] = sinf(v);
}

// ---------------- RoPE + split + V-transpose pre-pass.
// qkv fp32 [row][h*192 + {q|k|v}*64 + d] ->
//   Qp/Kp planes [bh][s][d] (rope'd, hi/lo), Vt planes [bh][d][s] (hi/lo)
__global__ __launch_bounds__(256) void rope_split(const float* __restrict__ qkv,
        const float* __restrict__ ct, const float* __restrict__ st,
        unsigned short* __restrict__ Qh, unsigned short* __restrict__ Ql,
        unsigned short* __restrict__ Kh, unsigned short* __restrict__ Kl,
        unsigned short* __restrict__ Vh, unsigned short* __restrict__ Vl) {
    __shared__ unsigned short svh[64][72], svl[64][72];   // transposed V tile [d][kv]
    const int t = threadIdx.x;
    const int tile = blockIdx.x, bh = blockIdx.y;
    const int b = bh >> 4, h = bh & 15;
    const int r = t >> 2;          // local row 0..63
    const int p = t & 3;
    const int srow = tile * 64 + r;
    const float* base = qkv + ((size_t)(b * NS + srow)) * TDQ + h * 192;

    // --- Q and K: rope + split, write planes
#pragma unroll
    for (int qk = 0; qk < 2; ++qk) {
        const float* src = base + qk * 64;
        float a[8], c[8], o1[8], o2[8];
#pragma unroll
        for (int j = 0; j < 8; ++j) {
            a[j] = src[p * 8 + j];
            c[j] = src[32 + p * 8 + j];
        }
#pragma unroll
        for (int j = 0; j < 8; ++j) {
            int d1 = p * 8 + j, d2 = 32 + p * 8 + j;
            float c1 = ct[(size_t)srow * HDD + d1], s1 = st[(size_t)srow * HDD + d1];
            float c2 = ct[(size_t)srow * HDD + d2], s2 = st[(size_t)srow * HDD + d2];
            o1[j] = a[j] * c1 - c[j] * s1;    // rot = -x[d+32]
            o2[j] = c[j] * c2 + a[j] * s2;    // rot =  x[d-32]
        }
        us8 h1, l1, h2, l2;
#pragma unroll
        for (int j = 0; j < 8; ++j) {
            unsigned short hh, ll;
            splitbf(o1[j], hh, ll); h1[j] = hh; l1[j] = ll;
            splitbf(o2[j], hh, ll); h2[j] = hh; l2[j] = ll;
        }
        unsigned short* dsth = qk ? Kh : Qh;
        unsigned short* dstl = qk ? Kl : Ql;
        size_t obase = ((size_t)bh * NS + srow) * HDD;
        *reinterpret_cast<us8*>(dsth + obase + p * 8)      = h1;
        *reinterpret_cast<us8*>(dsth + obase + 32 + p * 8) = h2;
        *reinterpret_cast<us8*>(dstl + obase + p * 8)      = l1;
        *reinterpret_cast<us8*>(dstl + obase + 32 + p * 8) = l2;
    }
    // --- V: split + transpose via LDS
    const float* vsrc = base + 128;
#pragma unroll
    for (int j = 0; j < 16; ++j) {
        unsigned short hh, ll;
        splitbf(vsrc[p * 16 + j], hh, ll);
        svh[p * 16 + j][r] = hh;
        svl[p * 16 + j][r] = ll;
    }
    __syncthreads();
    {
        int d = t >> 2, kb = (t & 3) * 16;
        size_t obase = ((size_t)bh * HDD + d) * NS + tile * 64 + kb;
        *reinterpret_cast<us8*>(Vh + obase)     = *reinterpret_cast<us8*>(&svh[d][kb]);
        *reinterpret_cast<us8*>(Vh + obase + 8) = *reinterpret_cast<us8*>(&svh[d][kb + 8]);
        *reinterpret_cast<us8*>(Vl + obase)     = *reinterpret_cast<us8*>(&svl[d][kb]);
        *reinterpret_cast<us8*>(Vl + obase + 8) = *reinterpret_cast<us8*>(&svl[d][kb + 8]);
    }
}

// ---------------- Flash attention, split-bf16 MFMA.
// Block: 4 waves, 64 q-rows (wave w owns rows w*16..w*16+16), K-tiles of 64.
// mfma 16x16x32: A lane: row=l&15, k=(l>>4)*8+j ; B lane: col=l&15, k=(l>>4)*8+j ;
// C/D lane: col=l&15, row=(l>>4)*4+reg  [m89-verified layouts]
__global__ __launch_bounds__(256) void attn_mfma(
        const unsigned short* __restrict__ Qh, const unsigned short* __restrict__ Ql,
        const unsigned short* __restrict__ Kh, const unsigned short* __restrict__ Kl,
        const unsigned short* __restrict__ Vh, const unsigned short* __restrict__ Vl,
        const float* __restrict__ pos_bias, const int* __restrict__ mask,
        unsigned short* __restrict__ valh, unsigned short* __restrict__ vall) {
    __shared__ unsigned short kH[64][72], kL[64][72];   // [kv][d], stride 144B (16-aligned)
    __shared__ unsigned short vH[64][72], vL[64][72];   // [d][kv] (pre-transposed source)
    __shared__ unsigned short pH[4][16][72], pL[4][16][72];  // per-wave P [q][kv]
    const int t = threadIdx.x;
    const int w = t >> 6, lane = t & 63, lq = lane & 15, lg = lane >> 4;
    const int qt = blockIdx.x, bh = blockIdx.y;
    const int b = bh >> 4, h = bh & 15;
    const int q0 = qt * 64;

    // Q fragments held in registers for the whole kernel (rows q0+w*16+lq)
    bfrag qfh[2], qfl[2];
    {
        size_t qbase = ((size_t)bh * NS + q0 + w * 16 + lq) * HDD;
        qfh[0] = *reinterpret_cast<const bfrag*>(Qh + qbase + lg * 8);
        qfh[1] = *reinterpret_cast<const bfrag*>(Qh + qbase + 32 + lg * 8);
        qfl[0] = *reinterpret_cast<const bfrag*>(Ql + qbase + lg * 8);
        qfl[1] = *reinterpret_cast<const bfrag*>(Ql + qbase + 32 + lg * 8);
    }
    f32x4 o[4];
    float mrow[4], lrow[4];
#pragma unroll
    for (int f = 0; f < 4; ++f) o[f] = (f32x4)0.0f;
#pragma unroll
    for (int r = 0; r < 4; ++r) { mrow[r] = -INFINITY; lrow[r] = 0.0f; }

    // staging indices: K: rows c*32 + t/8, dcol (t&7)*8 ; V: d-rows c*32 + t/8, kvcol (t&7)*8
    const int srw = t >> 3;          // 0..31
    const int sc8 = (t & 7) * 8;     // 0..56

    for (int kt = 0; kt < NS / 64; ++kt) {
        const int kv0 = kt * 64;
        // bias + mask loads early (overlap with staging / MFMA latency)
        float bb[4][4]; int mm[4][4];
#pragma unroll
        for (int f = 0; f < 4; ++f)
#pragma unroll
            for (int r = 0; r < 4; ++r) {
                int gq = q0 + w * 16 + lg * 4 + r;
                int gk = kv0 + f * 16 + lq;
                bb[f][r] = pos_bias[((size_t)h * NS + gq) * NS + gk];
                mm[f][r] = mask[(size_t)gq * NS + gk];
            }
        // stage K/V tile
        size_t kbase = ((size_t)bh * NS + kv0 + srw) * HDD + sc8;
        size_t vbase = ((size_t)bh * HDD + srw) * NS + kv0 + sc8;
        us8 k0a = *reinterpret_cast<const us8*>(Kh + kbase);
        us8 k0b = *reinterpret_cast<const us8*>(Kh + kbase + (size_t)32 * HDD);
        us8 k1a = *reinterpret_cast<const us8*>(Kl + kbase);
        us8 k1b = *reinterpret_cast<const us8*>(Kl + kbase + (size_t)32 * HDD);
        us8 v0a = *reinterpret_cast<const us8*>(Vh + vbase);
        us8 v0b = *reinterpret_cast<const us8*>(Vh + vbase + (size_t)32 * NS);
        us8 v1a = *reinterpret_cast<const us8*>(Vl + vbase);
        us8 v1b = *reinterpret_cast<const us8*>(Vl + vbase + (size_t)32 * NS);
        __syncthreads();   // prior tile's LDS reads complete
        *reinterpret_cast<us8*>(&kH[srw][sc8])      = k0a;
        *reinterpret_cast<us8*>(&kH[32 + srw][sc8]) = k0b;
        *reinterpret_cast<us8*>(&kL[srw][sc8])      = k1a;
        *reinterpret_cast<us8*>(&kL[32 + srw][sc8]) = k1b;
        *reinterpret_cast<us8*>(&vH[srw][sc8])      = v0a;
        *reinterpret_cast<us8*>(&vH[32 + srw][sc8]) = v0b;
        *reinterpret_cast<us8*>(&vL[srw][sc8])      = v1a;
        *reinterpret_cast<us8*>(&vL[32 + srw][sc8]) = v1b;
        __syncthreads();

        // S = Q K^T (3-term split)
        f32x4 s[4];
#pragma unroll
        for (int n = 0; n < 4; ++n) s[n] = (f32x4)0.0f;
#pragma unroll
        for (int n = 0; n < 4; ++n)
#pragma unroll
            for (int ks = 0; ks < 2; ++ks) {
                bfrag kh_ = *reinterpret_cast<const bfrag*>(&kH[n * 16 + lq][ks * 32 + lg * 8]);
                bfrag kl_ = *reinterpret_cast<const bfrag*>(&kL[n * 16 + lq][ks * 32 + lg * 8]);
                s[n] = MFMA(qfh[ks], kh_, s[n]);
                s[n] = MFMA(qfh[ks], kl_, s[n]);
                s[n] = MFMA(qfl[ks], kh_, s[n]);
            }
        // bias, scale, mask (reference order), online softmax per row
        float sv[4][4];
#pragma unroll
        for (int n = 0; n < 4; ++n)
#pragma unroll
            for (int r = 0; r < 4; ++r) {
                float x = (s[n][r] + bb[n][r]) * 0.125f;
                sv[n][r] = (mm[n][r] == 0) ? -9.0e15f : x;
            }
        float corr[4];
#pragma unroll
        for (int r = 0; r < 4; ++r) {
            float mx = fmaxf(fmaxf(sv[0][r], sv[1][r]), fmaxf(sv[2][r], sv[3][r]));
#pragma unroll
            for (int off = 1; off < 16; off <<= 1) mx = fmaxf(mx, __shfl_xor(mx, off));
            float mnew = fmaxf(mrow[r], mx);
            corr[r] = __expf(mrow[r] - mnew);
            float ps = 0.0f;
#pragma unroll
            for (int n = 0; n < 4; ++n) {
                float p = __expf(sv[n][r] - mnew);
                ps += p;
                unsigned short hh, ll; splitbf(p, hh, ll);
                pH[w][lg * 4 + r][n * 16 + lq] = hh;
                pL[w][lg * 4 + r][n * 16 + lq] = ll;
            }
#pragma unroll
            for (int off = 1; off < 16; off <<= 1) ps += __shfl_xor(ps, off);
            lrow[r] = lrow[r] * corr[r] + ps;
            mrow[r] = mnew;
        }
        // O_tile = P V (3-term split); P frags from per-wave LDS
        bfrag pfh[2], pfl[2];
#pragma unroll
        for (int ks = 0; ks < 2; ++ks) {
            pfh[ks] = *reinterpret_cast<const bfrag*>(&pH[w][lq][ks * 32 + lg * 8]);
            pfl[ks] = *reinterpret_cast<const bfrag*>(&pL[w][lq][ks * 32 + lg * 8]);
        }
        f32x4 pv[4];
#pragma unroll
        for (int f = 0; f < 4; ++f) pv[f] = (f32x4)0.0f;
#pragma unroll
        for (int f = 0; f < 4; ++f)
#pragma unroll
            for (int ks = 0; ks < 2; ++ks) {
                bfrag vh_ = *reinterpret_cast<const bfrag*>(&vH[f * 16 + lq][ks * 32 + lg * 8]);
                bfrag vl_ = *reinterpret_cast<const bfrag*>(&vL[f * 16 + lq][ks * 32 + lg * 8]);
                pv[f] = MFMA(pfh[ks], vh_, pv[f]);
                pv[f] = MFMA(pfh[ks], vl_, pv[f]);
                pv[f] = MFMA(pfl[ks], vh_, pv[f]);
            }
#pragma unroll
        for (int f = 0; f < 4; ++f)
#pragma unroll
            for (int r = 0; r < 4; ++r)
                o[f][r] = o[f][r] * corr[r] + pv[f][r];
    }
    // epilogue: vals planes [row][h*64+d]
#pragma unroll
    for (int r = 0; r < 4; ++r) {
        float inv = 1.0f / lrow[r];
        size_t rowb = ((size_t)(b * NS + q0 + w * 16 + lg * 4 + r)) * DD + h * HDD;
#pragma unroll
        for (int f = 0; f < 4; ++f) {
            unsigned short hh, ll; splitbf(o[f][r] * inv, hh, ll);
            valh[rowb + f * 16 + lq] = hh;
            vall[rowb + f * 16 + lq] = ll;
        }
    }
}

// ---------------- split-bf16 MFMA GEMM: C = A @ B^T_planes (+bias [+resid] [gelu->planes])
// A planes [M][K], B planes [N][K] (pre-transposed weights). 128x128 tile, BK=32,
// 4 waves each computing 64x64 (4x4 fragments). EPI: 0=+bias fp32; 1=+bias+resid fp32;
// 2=gelu(+bias) -> hi/lo planes.
template<int EPI>
__global__ __launch_bounds__(256) void gemm_planes(
        const unsigned short* __restrict__ Ah, const unsigned short* __restrict__ Al,
        const unsigned short* __restrict__ Bh, const unsigned short* __restrict__ Bl,
        const float* __restrict__ bias, const float* __restrict__ resid,
        float* __restrict__ Cf, unsigned short* __restrict__ Ch, unsigned short* __restrict__ Cl,
        int M, int N, int K) {
    __shared__ unsigned short sAh[128][40], sAl[128][40];   // stride 80B (16-aligned)
    __shared__ unsigned short sBh[128][40], sBl[128][40];
    const int t = threadIdx.x;
    const int w = t >> 6, lane = t & 63, lq = lane & 15, lg = lane >> 4;
    const int wr = w >> 1, wc = w & 1;
    const int m0 = blockIdx.y * 128, n0 = blockIdx.x * 128;

    f32x4 acc[4][4];
#pragma unroll
    for (int m = 0; m < 4; ++m)
#pragma unroll
        for (int n = 0; n < 4; ++n) acc[m][n] = (f32x4)0.0f;

    const int sr = t >> 2;          // 0..63
    const int sk = (t & 3) * 8;     // 0,8,16,24
    const unsigned short* pAh0 = Ah + (size_t)(m0 + sr) * K + sk;
    const unsigned short* pAh1 = pAh0 + (size_t)64 * K;
    const unsigned short* pAl0 = Al + (size_t)(m0 + sr) * K + sk;
    const unsigned short* pAl1 = pAl0 + (size_t)64 * K;
    const unsigned short* pBh0 = Bh + (size_t)(n0 + sr) * K + sk;
    const unsigned short* pBh1 = pBh0 + (size_t)64 * K;
    const unsigned short* pBl0 = Bl + (size_t)(n0 + sr) * K + sk;
    const unsigned short* pBl1 = pBl0 + (size_t)64 * K;

    for (int k0 = 0; k0 < K; k0 += 32) {
        us8 a0 = *reinterpret_cast<const us8*>(pAh0 + k0);
        us8 a1 = *reinterpret_cast<const us8*>(pAh1 + k0);
        us8 a2 = *reinterpret_cast<const us8*>(pAl0 + k0);
        us8 a3 = *reinterpret_cast<const us8*>(pAl1 + k0);
        us8 b0 = *reinterpret_cast<const us8*>(pBh0 + k0);
        us8 b1 = *reinterpret_cast<const us8*>(pBh1 + k0);
        us8 b2 = *reinterpret_cast<const us8*>(pBl0 + k0);
        us8 b3 = *reinterpret_cast<const us8*>(pBl1 + k0);
        __syncthreads();
        *reinterpret_cast<us8*>(&sAh[sr][sk])      = a0;
        *reinterpret_cast<us8*>(&sAh[64 + sr][sk]) = a1;
        *reinterpret_cast<us8*>(&sAl[sr][sk])      = a2;
        *reinterpret_cast<us8*>(&sAl[64 + sr][sk]) = a3;
        *reinterpret_cast<us8*>(&sBh[sr][sk])      = b0;
        *reinterpret_cast<us8*>(&sBh[64 + sr][sk]) = b1;
        *reinterpret_cast<us8*>(&sBl[sr][sk])      = b2;
        *reinterpret_cast<us8*>(&sBl[64 + sr][sk]) = b3;
        __syncthreads();
        bfrag fah[4], fal[4], fbh[4], fbl[4];
#pragma unroll
        for (int m = 0; m < 4; ++m) {
            fah[m] = *reinterpret_cast<const bfrag*>(&sAh[wr * 64 + m * 16 + lq][lg * 8]);
            fal[m] = *reinterpret_cast<const bfrag*>(&sAl[wr * 64 + m * 16 + lq][lg * 8]);
        }
#pragma unroll
        for (int n = 0; n < 4; ++n) {
            fbh[n] = *reinterpret_cast<const bfrag*>(&sBh[wc * 64 + n * 16 + lq][lg * 8]);
            fbl[n] = *reinterpret_cast<const bfrag*>(&sBl[wc * 64 + n * 16 + lq][lg * 8]);
        }
#pragma unroll
        for (int m = 0; m < 4; ++m)
#pragma unroll
            for (int n = 0; n < 4; ++n) {
                acc[m][n] = MFMA(fah[m], fbh[n], acc[m][n]);
                acc[m][n] = MFMA(fah[m], fbl[n], acc[m][n]);
                acc[m][n] = MFMA(fal[m], fbh[n], acc[m][n]);
            }
    }
    // epilogue: C/D lane mapping col=lq, row=lg*4+r
#pragma unroll
    for (int m = 0; m < 4; ++m)
#pragma unroll
        for (int r = 0; r < 4; ++r) {
            int row = m0 + wr * 64 + m * 16 + lg * 4 + r;
#pragma unroll
            for (int n = 0; n < 4; ++n) {
                int col = n0 + wc * 64 + n * 16 + lq;
                float v = acc[m][n][r] + bias[col];
                if (EPI == 1) v += resid[(size_t)row * N + col];
                if (EPI == 2) {
                    v = gelu_f(v);
                    unsigned short hh, ll; splitbf(v, hh, ll);
                    Ch[(size_t)row * N + col] = hh;
                    Cl[(size_t)row * N + col] = ll;
                } else {
                    Cf[(size_t)row * N + col] = v;
                }
            }
        }
}

extern "C" void kernel_launch(void* const* d_in, const int* in_sizes, int n_in,
                              void* d_out, int out_size, void* d_ws, size_t ws_size,
                              hipStream_t stream) {
    const float* x        = (const float*)d_in[0];
    const int*   mask     = (const int*)d_in[1];
    const float* pos_bias = (const float*)d_in[2];
    const float* sp       = (const float*)d_in[3];
    const float* Wqkv     = (const float*)d_in[4];
    const float* bqkv     = (const float*)d_in[5];
    const float* Wo       = (const float*)d_in[6];
    const float* bo       = (const float*)d_in[7];
    const float* W1       = (const float*)d_in[8];
    const float* b1       = (const float*)d_in[9];
    const float* W2       = (const float*)d_in[10];
    const float* b2       = (const float*)d_in[11];
    const float* g1       = (const float*)d_in[12];
    const float* be1      = (const float*)d_in[13];
    const float* g2       = (const float*)d_in[14];
    const float* be2      = (const float*)d_in[15];
    float* out = (float*)d_out;
    char* wsb = (char*)d_ws;

    // ws layout (144 MB total):
    //  [0,16M)    xbuf fp32 (xn -> x1 -> x2)
    //  [16,24M)   actH ; [24,32M) actL   (xn planes -> vals planes -> x2 planes)
    //  [32,40M)   wTh ; [40,48M) wTl     (per-weight, serial reuse; cos/sin tables too)
    //  [48,96M)   qkv fp32
    //  [96,144M)  attn planes: Qh,Ql,Kh,Kl,Vth,Vtl (8 MB each)
    //  h planes overlap: hH @48M (32MB), hL @80M (32MB) — qkv/Q planes dead by then
    float*          xbuf = (float*)(wsb);
    unsigned short* actH = (unsigned short*)(wsb + ((size_t)16 << 20));
    unsigned short* actL = (unsigned short*)(wsb + ((size_t)24 << 20));
    unsigned short* wTh  = (unsigned short*)(wsb + ((size_t)32 << 20));
    unsigned short* wTl  = (unsigned short*)(wsb + ((size_t)40 << 20));
    float*          ct   = (float*)(wsb + ((size_t)32 << 20));
    float*          stb  = (float*)(wsb + ((size_t)33 << 20));
    float*          qkv  = (float*)(wsb + ((size_t)48 << 20));
    unsigned short* Qph  = (unsigned short*)(wsb + ((size_t)96  << 20));
    unsigned short* Qpl  = (unsigned short*)(wsb + ((size_t)104 << 20));
    unsigned short* Kph  = (unsigned short*)(wsb + ((size_t)112 << 20));
    unsigned short* Kpl  = (unsigned short*)(wsb + ((size_t)120 << 20));
    unsigned short* Vth  = (unsigned short*)(wsb + ((size_t)128 << 20));
    unsigned short* Vtl  = (unsigned short*)(wsb + ((size_t)136 << 20));
    unsigned short* hH   = (unsigned short*)(wsb + ((size_t)48 << 20));
    unsigned short* hL   = (unsigned short*)(wsb + ((size_t)80 << 20));

    // 1. xn = LN1(x) -> fp32 + planes
    ln_kernel<<<NR, 256, 0, stream>>>(x, g1, be1, xbuf, actH, actL);
    // 2. qkv = xn @ Wqkv + bqkv
    wt_convert<<<dim3(TDQ / 32, DD / 32), 256, 0, stream>>>(Wqkv, wTh, wTl, DD, TDQ);
    gemm_planes<0><<<dim3(TDQ / 128, NR / 128), 256, 0, stream>>>(
        actH, actL, wTh, wTl, bqkv, nullptr, qkv, nullptr, nullptr, NR, TDQ, DD);
    // 3. RoPE + split + V transpose
    cs_table<<<(NS * HDD) / 256, 256, 0, stream>>>(sp, ct, stb);
    rope_split<<<dim3(NS / 64, NB * HH), 256, 0, stream>>>(qkv, ct, stb,
        Qph, Qpl, Kph, Kpl, Vth, Vtl);
    // 4. vals = attention -> planes (into actH/actL; xn planes dead)
    attn_mfma<<<dim3(NS / 64, NB * HH), 256, 0, stream>>>(
        Qph, Qpl, Kph, Kpl, Vth, Vtl, pos_bias, mask, actH, actL);
    // 5. x1 = xn + vals @ Wo + bo (in-place over xbuf)
    wt_convert<<<dim3(DD / 32, DD / 32), 256, 0, stream>>>(Wo, wTh, wTl, DD, DD);
    gemm_planes<1><<<dim3(DD / 128, NR / 128), 256, 0, stream>>>(
        actH, actL, wTh, wTl, bo, xbuf, xbuf, nullptr, nullptr, NR, DD, DD);
    // 6. x2 = LN2(x1) -> fp32 (in place) + planes
    ln_kernel<<<NR, 256, 0, stream>>>(xbuf, g2, be2, xbuf, actH, actL);
    // 7. h = gelu(x2 @ W1 + b1) -> planes
    wt_convert<<<dim3(FFF / 32, DD / 32), 256, 0, stream>>>(W1, wTh, wTl, DD, FFF);
    gemm_planes<2><<<dim3(FFF / 128, NR / 128), 256, 0, stream>>>(
        actH, actL, wTh, wTl, b1, nullptr, nullptr, hH, hL, NR, FFF, DD);
    // 8. out = x2 + h @ W2 + b2
    wt_convert<<<dim3(DD / 32, FFF / 32), 256, 0, stream>>>(W2, wTh, wTl, FFF, DD);
    gemm_planes<1><<<dim3(DD / 128, NR / 128), 256, 0, stream>>>(
        hH, hL, wTh, wTl, b2, xbuf, out, nullptr, nullptr, NR, DD, FFF);
}

// Round 3
// 756.719 us; speedup vs baseline: 4.1224x; 1.0202x over previous
//
#include <hip/hip_runtime.h>
#include <math.h>

// Problem constants (B=2, S=2048, D=1024, H=16, HD=64, FF=4096)
#define DD   1024
#define HH   16
#define HDD  64
#define FFF  4096
#define NB   2
#define NS   2048
#define NR   (NB * NS)     // 4096 rows
#define TDQ  (3 * DD)      // 3072

typedef __attribute__((ext_vector_type(8))) short bfrag;          // 8 bf16 (MFMA A/B operand)
typedef __attribute__((ext_vector_type(4))) float f32x4;          // MFMA C/D
typedef __attribute__((ext_vector_type(8))) unsigned short us8;   // 16B staging chunk
typedef __attribute__((ext_vector_type(4))) unsigned short us4;

__device__ __forceinline__ float4 ld4(const float* p) {
    return *reinterpret_cast<const float4*>(p);
}
__device__ __forceinline__ unsigned short f2bf(float x) {   // round-to-nearest-even bf16
    unsigned int u = __float_as_uint(x);
    u += 0x7fffu + ((u >> 16) & 1u);
    return (unsigned short)(u >> 16);
}
__device__ __forceinline__ float bf2f(unsigned short h) {
    return __uint_as_float(((unsigned int)h) << 16);
}
__device__ __forceinline__ void splitbf(float x, unsigned short& hi, unsigned short& lo) {
    hi = f2bf(x);
    lo = f2bf(x - bf2f(hi));
}
__device__ __forceinline__ float gelu_f(float x) {
    return 0.5f * x * (1.0f + erff(x * 0.70710678118654752440f));
}
#define MFMA(a, b, c) __builtin_amdgcn_mfma_f32_16x16x32_bf16((a), (b), (c), 0, 0, 0)

// ---------------- LayerNorm: fp32 out + hi/lo bf16 planes
__global__ __launch_bounds__(256) void ln_kernel(const float* __restrict__ in,
        const float* __restrict__ gw, const float* __restrict__ bw,
        float* __restrict__ outf, unsigned short* __restrict__ oh,
        unsigned short* __restrict__ ol) {
    int row = blockIdx.x;
    float4 v = reinterpret_cast<const float4*>(in + (size_t)row * DD)[threadIdx.x];
    float s1 = v.x + v.y + v.z + v.w;
    float s2 = v.x * v.x + v.y * v.y + v.z * v.z + v.w * v.w;
#pragma unroll
    for (int off = 1; off < 64; off <<= 1) {
        s1 += __shfl_xor(s1, off);
        s2 += __shfl_xor(s2, off);
    }
    __shared__ float r1[4], r2[4];
    int wid = threadIdx.x >> 6;
    if ((threadIdx.x & 63) == 0) { r1[wid] = s1; r2[wid] = s2; }
    __syncthreads();
    s1 = r1[0] + r1[1] + r1[2] + r1[3];
    s2 = r2[0] + r2[1] + r2[2] + r2[3];
    float mu   = s1 * (1.0f / DD);
    float var  = s2 * (1.0f / DD) - mu * mu;
    float rstd = rsqrtf(var + 1e-5f);
    float4 g = reinterpret_cast<const float4*>(gw)[threadIdx.x];
    float4 b = reinterpret_cast<const float4*>(bw)[threadIdx.x];
    float o[4];
    o[0] = (v.x - mu) * rstd * g.x + b.x;
    o[1] = (v.y - mu) * rstd * g.y + b.y;
    o[2] = (v.z - mu) * rstd * g.z + b.z;
    o[3] = (v.w - mu) * rstd * g.w + b.w;
    float4 of; of.x = o[0]; of.y = o[1]; of.z = o[2]; of.w = o[3];
    reinterpret_cast<float4*>(outf + (size_t)row * DD)[threadIdx.x] = of;
    us4 h4, l4;
#pragma unroll
    for (int j = 0; j < 4; ++j) { unsigned short hh, ll; splitbf(o[j], hh, ll); h4[j] = hh; l4[j] = ll; }
    *reinterpret_cast<us4*>(oh + (size_t)row * DD + threadIdx.x * 4) = h4;
    *reinterpret_cast<us4*>(ol + (size_t)row * DD + threadIdx.x * 4) = l4;
}

// ---------------- Weight transpose+split: W[K][N] fp32 -> Th/Tl[N][K] bf16
__global__ __launch_bounds__(256) void wt_convert(const float* __restrict__ W,
        unsigned short* __restrict__ Th, unsigned short* __restrict__ Tl, int K, int N) {
    __shared__ float s[32][33];
    int tx = threadIdx.x & 31, ty = threadIdx.x >> 5;   // ty 0..7
    int n0 = blockIdx.x * 32, k0 = blockIdx.y * 32;
#pragma unroll
    for (int i = 0; i < 4; ++i)
        s[ty + i * 8][tx] = W[(size_t)(k0 + ty + i * 8) * N + n0 + tx];
    __syncthreads();
#pragma unroll
    for (int i = 0; i < 4; ++i) {
        int n = n0 + ty + i * 8;
        float v = s[tx][ty + i * 8];
        unsigned short h, l; splitbf(v, h, l);
        Th[(size_t)n * K + k0 + tx] = h;
        Tl[(size_t)n * K + k0 + tx] = l;
    }
}

// ---------------- cos/sin tables for RoPE: [S][HD]
__global__ __launch_bounds__(256) void cs_table(const float* __restrict__ sp,
        float* __restrict__ ct, float* __restrict__ st) {
    int i = blockIdx.x * 256 + threadIdx.x;   // NS*HDD total
    float v = sp[i];
    ct[i] = cosf(v);
    st[i] = sinf(v);
}

// ---------------- RoPE + split + V-transpose pre-pass.
__global__ __launch_bounds__(256) void rope_split(const float* __restrict__ qkv,
        const float* __restrict__ ct, const float* __restrict__ st,
        unsigned short* __restrict__ Qh, unsigned short* __restrict__ Ql,
        unsigned short* __restrict__ Kh, unsigned short* __restrict__ Kl,
        unsigned short* __restrict__ Vh, unsigned short* __restrict__ Vl) {
    __shared__ unsigned short svh[64][72], svl[64][72];   // transposed V tile [d][kv]
    const int t = threadIdx.x;
    const int tile = blockIdx.x, bh = blockIdx.y;
    const int b = bh >> 4, h = bh & 15;
    const int r = t >> 2;          // local row 0..63
    const int p = t & 3;
    const int srow = tile * 64 + r;
    const float* base = qkv + ((size_t)(b * NS + srow)) * TDQ + h * 192;

#pragma unroll
    for (int qk = 0; qk < 2; ++qk) {
        const float* src = base + qk * 64;
        float a[8], c[8], o1[8], o2[8];
#pragma unroll
        for (int j = 0; j < 8; ++j) {
            a[j] = src[p * 8 + j];
            c[j] = src[32 + p * 8 + j];
        }
#pragma unroll
        for (int j = 0; j < 8; ++j) {
            int d1 = p * 8 + j, d2 = 32 + p * 8 + j;
            float c1 = ct[(size_t)srow * HDD + d1], s1 = st[(size_t)srow * HDD + d1];
            float c2 = ct[(size_t)srow * HDD + d2], s2 = st[(size_t)srow * HDD + d2];
            o1[j] = a[j] * c1 - c[j] * s1;
            o2[j] = c[j] * c2 + a[j] * s2;
        }
        us8 h1, l1, h2, l2;
#pragma unroll
        for (int j = 0; j < 8; ++j) {
            unsigned short hh, ll;
            splitbf(o1[j], hh, ll); h1[j] = hh; l1[j] = ll;
            splitbf(o2[j], hh, ll); h2[j] = hh; l2[j] = ll;
        }
        unsigned short* dsth = qk ? Kh : Qh;
        unsigned short* dstl = qk ? Kl : Ql;
        size_t obase = ((size_t)bh * NS + srow) * HDD;
        *reinterpret_cast<us8*>(dsth + obase + p * 8)      = h1;
        *reinterpret_cast<us8*>(dsth + obase + 32 + p * 8) = h2;
        *reinterpret_cast<us8*>(dstl + obase + p * 8)      = l1;
        *reinterpret_cast<us8*>(dstl + obase + 32 + p * 8) = l2;
    }
    const float* vsrc = base + 128;
#pragma unroll
    for (int j = 0; j < 16; ++j) {
        unsigned short hh, ll;
        splitbf(vsrc[p * 16 + j], hh, ll);
        svh[p * 16 + j][r] = hh;
        svl[p * 16 + j][r] = ll;
    }
    __syncthreads();
    {
        int d = t >> 2, kb = (t & 3) * 16;
        size_t obase = ((size_t)bh * HDD + d) * NS + tile * 64 + kb;
        *reinterpret_cast<us8*>(Vh + obase)     = *reinterpret_cast<us8*>(&svh[d][kb]);
        *reinterpret_cast<us8*>(Vh + obase + 8) = *reinterpret_cast<us8*>(&svh[d][kb + 8]);
        *reinterpret_cast<us8*>(Vl + obase)     = *reinterpret_cast<us8*>(&svl[d][kb]);
        *reinterpret_cast<us8*>(Vl + obase + 8) = *reinterpret_cast<us8*>(&svl[d][kb + 8]);
    }
}

// ---------------- Flash attention, split-bf16 MFMA, pipelined + LDS-staged bias.
// Grid y: h = y>>1, b = y&1 (batch pairs adjacent -> same XCD -> pos_bias L2 reuse).
__global__ __launch_bounds__(256) void attn_mfma(
        const unsigned short* __restrict__ Qh, const unsigned short* __restrict__ Ql,
        const unsigned short* __restrict__ Kh, const unsigned short* __restrict__ Kl,
        const unsigned short* __restrict__ Vh, const unsigned short* __restrict__ Vl,
        const float* __restrict__ pos_bias, const int* __restrict__ mask,
        unsigned short* __restrict__ valh, unsigned short* __restrict__ vall) {
    __shared__ unsigned short kH[64][72], kL[64][72];   // [kv][d]
    __shared__ unsigned short vH[64][72], vL[64][72];   // [d][kv]
    __shared__ float pF[4][16][68];                     // per-wave P (fp32)
    __shared__ float PBs[64][68];                       // masked bias, log2 domain
    const int t = threadIdx.x;
    const int w = t >> 6, lane = t & 63, lq = lane & 15, lg = lane >> 4;
    const int qt = blockIdx.x;
    const int h = blockIdx.y >> 1, b = blockIdx.y & 1;
    const int bh = b * HH + h;
    const int q0 = qt * 64;
    const float C1   = 0.18033688011112042f;   // 0.125 * log2(e)
    const float NEGL = -1.0e15f;
    const float THR  = 11.5f;                  // ~8 nats in log2 units

    bfrag qfh[2], qfl[2];
    {
        size_t qbase = ((size_t)bh * NS + q0 + w * 16 + lq) * HDD;
        qfh[0] = *reinterpret_cast<const bfrag*>(Qh + qbase + lg * 8);
        qfh[1] = *reinterpret_cast<const bfrag*>(Qh + qbase + 32 + lg * 8);
        qfl[0] = *reinterpret_cast<const bfrag*>(Ql + qbase + lg * 8);
        qfl[1] = *reinterpret_cast<const bfrag*>(Ql + qbase + 32 + lg * 8);
    }
    f32x4 o[4];
    float mrow[4], lrow[4];
#pragma unroll
    for (int f = 0; f < 4; ++f) o[f] = (f32x4)0.0f;
#pragma unroll
    for (int r = 0; r < 4; ++r) { mrow[r] = -INFINITY; lrow[r] = 0.0f; }

    const int srw = t >> 3, sc8 = (t & 7) * 8;      // K/V staging
    const int pbr = t >> 2, pbc = (t & 3) * 16;     // bias staging

    us8 kr[4], vr[4];
    float4 pb4[4]; int4 mk4[4];

#define ATTN_LOAD(KT) {                                                        \
        int kv0_ = (KT) * 64;                                                  \
        size_t kb_ = ((size_t)bh * NS + kv0_ + srw) * HDD + sc8;               \
        size_t vb_ = ((size_t)bh * HDD + srw) * NS + kv0_ + sc8;               \
        kr[0] = *reinterpret_cast<const us8*>(Kh + kb_);                       \
        kr[1] = *reinterpret_cast<const us8*>(Kh + kb_ + (size_t)32 * HDD);    \
        kr[2] = *reinterpret_cast<const us8*>(Kl + kb_);                       \
        kr[3] = *reinterpret_cast<const us8*>(Kl + kb_ + (size_t)32 * HDD);    \
        vr[0] = *reinterpret_cast<const us8*>(Vh + vb_);                       \
        vr[1] = *reinterpret_cast<const us8*>(Vh + vb_ + (size_t)32 * NS);     \
        vr[2] = *reinterpret_cast<const us8*>(Vl + vb_);                       \
        vr[3] = *reinterpret_cast<const us8*>(Vl + vb_ + (size_t)32 * NS);     \
        const float* pbp_ = pos_bias + ((size_t)h * NS + q0 + pbr) * NS + kv0_ + pbc; \
        const int*   mkp_ = mask + (size_t)(q0 + pbr) * NS + kv0_ + pbc;       \
        _Pragma("unroll")                                                      \
        for (int j = 0; j < 4; ++j) {                                          \
            pb4[j] = ld4(pbp_ + 4 * j);                                        \
            mk4[j] = *reinterpret_cast<const int4*>(mkp_ + 4 * j);             \
        }                                                                      \
    }

    ATTN_LOAD(0);
    for (int kt = 0; kt < NS / 64; ++kt) {
        __syncthreads();   // prior tile's LDS reads complete
        *reinterpret_cast<us8*>(&kH[srw][sc8])      = kr[0];
        *reinterpret_cast<us8*>(&kH[32 + srw][sc8]) = kr[1];
        *reinterpret_cast<us8*>(&kL[srw][sc8])      = kr[2];
        *reinterpret_cast<us8*>(&kL[32 + srw][sc8]) = kr[3];
        *reinterpret_cast<us8*>(&vH[srw][sc8])      = vr[0];
        *reinterpret_cast<us8*>(&vH[32 + srw][sc8]) = vr[1];
        *reinterpret_cast<us8*>(&vL[srw][sc8])      = vr[2];
        *reinterpret_cast<us8*>(&vL[32 + srw][sc8]) = vr[3];
#pragma unroll
        for (int j = 0; j < 4; ++j) {
            float4 pv;
            pv.x = mk4[j].x ? pb4[j].x * C1 : NEGL;
            pv.y = mk4[j].y ? pb4[j].y * C1 : NEGL;
            pv.z = mk4[j].z ? pb4[j].z * C1 : NEGL;
            pv.w = mk4[j].w ? pb4[j].w * C1 : NEGL;
            *reinterpret_cast<float4*>(&PBs[pbr][pbc + 4 * j]) = pv;
        }
        __syncthreads();
        if (kt + 1 < NS / 64) ATTN_LOAD(kt + 1);   // prefetch under compute

        // S = Q K^T (3-term split)
        f32x4 s[4];
#pragma unroll
        for (int n = 0; n < 4; ++n) s[n] = (f32x4)0.0f;
#pragma unroll
        for (int n = 0; n < 4; ++n)
#pragma unroll
            for (int ks = 0; ks < 2; ++ks) {
                bfrag kh_ = *reinterpret_cast<const bfrag*>(&kH[n * 16 + lq][ks * 32 + lg * 8]);
                bfrag kl_ = *reinterpret_cast<const bfrag*>(&kL[n * 16 + lq][ks * 32 + lg * 8]);
                s[n] = MFMA(qfh[ks], kh_, s[n]);
                s[n] = MFMA(qfh[ks], kl_, s[n]);
                s[n] = MFMA(qfl[ks], kh_, s[n]);
            }
        // logits in log2 domain + row max
        float sv[4][4], mx[4];
#pragma unroll
        for (int r = 0; r < 4; ++r) {
#pragma unroll
            for (int n = 0; n < 4; ++n)
                sv[n][r] = fmaf(s[n][r], C1, PBs[w * 16 + lg * 4 + r][n * 16 + lq]);
            float m0 = fmaxf(fmaxf(sv[0][r], sv[1][r]), fmaxf(sv[2][r], sv[3][r]));
#pragma unroll
            for (int off = 1; off < 16; off <<= 1) m0 = fmaxf(m0, __shfl_xor(m0, off));
            mx[r] = m0;
        }
        // defer-max: rescale only when a row max grows past THR
        bool need = false;
#pragma unroll
        for (int r = 0; r < 4; ++r) need = need | (mx[r] > mrow[r] + THR);
        if (__any((int)need)) {
#pragma unroll
            for (int r = 0; r < 4; ++r) {
                float mnew = fmaxf(mrow[r], mx[r]);
                float corr = __builtin_amdgcn_exp2f(mrow[r] - mnew);
                lrow[r] *= corr;
#pragma unroll
                for (int f = 0; f < 4; ++f) o[f][r] *= corr;
                mrow[r] = mnew;
            }
        }
        // P = exp2(sv - m), fp32 to LDS, row-sum via shuffles
#pragma unroll
        for (int r = 0; r < 4; ++r) {
            float ps = 0.0f;
#pragma unroll
            for (int n = 0; n < 4; ++n) {
                float p = __builtin_amdgcn_exp2f(sv[n][r] - mrow[r]);
                ps += p;
                pF[w][lg * 4 + r][n * 16 + lq] = p;
            }
#pragma unroll
            for (int off = 1; off < 16; off <<= 1) ps += __shfl_xor(ps, off);
            lrow[r] += ps;
        }
        // P frags: read fp32, truncate-split to hi/lo bf16
        bfrag pfh[2], pfl[2];
#pragma unroll
        for (int ks = 0; ks < 2; ++ks) {
            const float* pp = &pF[w][lq][ks * 32 + lg * 8];
            float4 pa = ld4(pp), pb = ld4(pp + 4);
            float p8[8] = {pa.x, pa.y, pa.z, pa.w, pb.x, pb.y, pb.z, pb.w};
#pragma unroll
            for (int j = 0; j < 8; ++j) {
                unsigned int u = __float_as_uint(p8[j]);
                unsigned int hb = u & 0xffff0000u;
                float lo = p8[j] - __uint_as_float(hb);
                pfh[ks][j] = (short)(hb >> 16);
                pfl[ks][j] = (short)f2bf(lo);
            }
        }
        // O += P V (accumulate directly into o via MFMA C-operand)
#pragma unroll
        for (int f = 0; f < 4; ++f)
#pragma unroll
            for (int ks = 0; ks < 2; ++ks) {
                bfrag vh_ = *reinterpret_cast<const bfrag*>(&vH[f * 16 + lq][ks * 32 + lg * 8]);
                bfrag vl_ = *reinterpret_cast<const bfrag*>(&vL[f * 16 + lq][ks * 32 + lg * 8]);
                o[f] = MFMA(pfh[ks], vh_, o[f]);
                o[f] = MFMA(pfh[ks], vl_, o[f]);
                o[f] = MFMA(pfl[ks], vh_, o[f]);
            }
    }
#undef ATTN_LOAD
    // epilogue: vals planes [row][h*64+d]
#pragma unroll
    for (int r = 0; r < 4; ++r) {
        float inv = 1.0f / lrow[r];
        size_t rowb = ((size_t)(b * NS + q0 + w * 16 + lg * 4 + r)) * DD + h * HDD;
#pragma unroll
        for (int f = 0; f < 4; ++f) {
            unsigned short hh, ll; splitbf(o[f][r] * inv, hh, ll);
            valh[rowb + f * 16 + lq] = hh;
            vall[rowb + f * 16 + lq] = ll;
        }
    }
}

// ---------------- split-bf16 MFMA GEMM (unchanged from round 2)
template<int EPI>
__global__ __launch_bounds__(256) void gemm_planes(
        const unsigned short* __restrict__ Ah, const unsigned short* __restrict__ Al,
        const unsigned short* __restrict__ Bh, const unsigned short* __restrict__ Bl,
        const float* __restrict__ bias, const float* __restrict__ resid,
        float* __restrict__ Cf, unsigned short* __restrict__ Ch, unsigned short* __restrict__ Cl,
        int M, int N, int K) {
    __shared__ unsigned short sAh[128][40], sAl[128][40];
    __shared__ unsigned short sBh[128][40], sBl[128][40];
    const int t = threadIdx.x;
    const int w = t >> 6, lane = t & 63, lq = lane & 15, lg = lane >> 4;
    const int wr = w >> 1, wc = w & 1;
    const int m0 = blockIdx.y * 128, n0 = blockIdx.x * 128;

    f32x4 acc[4][4];
#pragma unroll
    for (int m = 0; m < 4; ++m)
#pragma unroll
        for (int n = 0; n < 4; ++n) acc[m][n] = (f32x4)0.0f;

    const int sr = t >> 2;
    const int sk = (t & 3) * 8;
    const unsigned short* pAh0 = Ah + (size_t)(m0 + sr) * K + sk;
    const unsigned short* pAh1 = pAh0 + (size_t)64 * K;
    const unsigned short* pAl0 = Al + (size_t)(m0 + sr) * K + sk;
    const unsigned short* pAl1 = pAl0 + (size_t)64 * K;
    const unsigned short* pBh0 = Bh + (size_t)(n0 + sr) * K + sk;
    const unsigned short* pBh1 = pBh0 + (size_t)64 * K;
    const unsigned short* pBl0 = Bl + (size_t)(n0 + sr) * K + sk;
    const unsigned short* pBl1 = pBl0 + (size_t)64 * K;

    for (int k0 = 0; k0 < K; k0 += 32) {
        us8 a0 = *reinterpret_cast<const us8*>(pAh0 + k0);
        us8 a1 = *reinterpret_cast<const us8*>(pAh1 + k0);
        us8 a2 = *reinterpret_cast<const us8*>(pAl0 + k0);
        us8 a3 = *reinterpret_cast<const us8*>(pAl1 + k0);
        us8 b0 = *reinterpret_cast<const us8*>(pBh0 + k0);
        us8 b1 = *reinterpret_cast<const us8*>(pBh1 + k0);
        us8 b2 = *reinterpret_cast<const us8*>(pBl0 + k0);
        us8 b3 = *reinterpret_cast<const us8*>(pBl1 + k0);
        __syncthreads();
        *reinterpret_cast<us8*>(&sAh[sr][sk])      = a0;
        *reinterpret_cast<us8*>(&sAh[64 + sr][sk]) = a1;
        *reinterpret_cast<us8*>(&sAl[sr][sk])      = a2;
        *reinterpret_cast<us8*>(&sAl[64 + sr][sk]) = a3;
        *reinterpret_cast<us8*>(&sBh[sr][sk])      = b0;
        *reinterpret_cast<us8*>(&sBh[64 + sr][sk]) = b1;
        *reinterpret_cast<us8*>(&sBl[sr][sk])      = b2;
        *reinterpret_cast<us8*>(&sBl[64 + sr][sk]) = b3;
        __syncthreads();
        bfrag fah[4], fal[4], fbh[4], fbl[4];
#pragma unroll
        for (int m = 0; m < 4; ++m) {
            fah[m] = *reinterpret_cast<const bfrag*>(&sAh[wr * 64 + m * 16 + lq][lg * 8]);
            fal[m] = *reinterpret_cast<const bfrag*>(&sAl[wr * 64 + m * 16 + lq][lg * 8]);
        }
#pragma unroll
        for (int n = 0; n < 4; ++n) {
            fbh[n] = *reinterpret_cast<const bfrag*>(&sBh[wc * 64 + n * 16 + lq][lg * 8]);
            fbl[n] = *reinterpret_cast<const bfrag*>(&sBl[wc * 64 + n * 16 + lq][lg * 8]);
        }
#pragma unroll
        for (int m = 0; m < 4; ++m)
#pragma unroll
            for (int n = 0; n < 4; ++n) {
                acc[m][n] = MFMA(fah[m], fbh[n], acc[m][n]);
                acc[m][n] = MFMA(fah[m], fbl[n], acc[m][n]);
                acc[m][n] = MFMA(fal[m], fbh[n], acc[m][n]);
            }
    }
#pragma unroll
    for (int m = 0; m < 4; ++m)
#pragma unroll
        for (int r = 0; r < 4; ++r) {
            int row = m0 + wr * 64 + m * 16 + lg * 4 + r;
#pragma unroll
            for (int n = 0; n < 4; ++n) {
                int col = n0 + wc * 64 + n * 16 + lq;
                float v = acc[m][n][r] + bias[col];
                if (EPI == 1) v += resid[(size_t)row * N + col];
                if (EPI == 2) {
                    v = gelu_f(v);
                    unsigned short hh, ll; splitbf(v, hh, ll);
                    Ch[(size_t)row * N + col] = hh;
                    Cl[(size_t)row * N + col] = ll;
                } else {
                    Cf[(size_t)row * N + col] = v;
                }
            }
        }
}

extern "C" void kernel_launch(void* const* d_in, const int* in_sizes, int n_in,
                              void* d_out, int out_size, void* d_ws, size_t ws_size,
                              hipStream_t stream) {
    const float* x        = (const float*)d_in[0];
    const int*   mask     = (const int*)d_in[1];
    const float* pos_bias = (const float*)d_in[2];
    const float* sp       = (const float*)d_in[3];
    const float* Wqkv     = (const float*)d_in[4];
    const float* bqkv     = (const float*)d_in[5];
    const float* Wo       = (const float*)d_in[6];
    const float* bo       = (const float*)d_in[7];
    const float* W1       = (const float*)d_in[8];
    const float* b1       = (const float*)d_in[9];
    const float* W2       = (const float*)d_in[10];
    const float* b2       = (const float*)d_in[11];
    const float* g1       = (const float*)d_in[12];
    const float* be1      = (const float*)d_in[13];
    const float* g2       = (const float*)d_in[14];
    const float* be2      = (const float*)d_in[15];
    float* out = (float*)d_out;
    char* wsb = (char*)d_ws;

    float*          xbuf = (float*)(wsb);
    unsigned short* actH = (unsigned short*)(wsb + ((size_t)16 << 20));
    unsigned short* actL = (unsigned short*)(wsb + ((size_t)24 << 20));
    unsigned short* wTh  = (unsigned short*)(wsb + ((size_t)32 << 20));
    unsigned short* wTl  = (unsigned short*)(wsb + ((size_t)40 << 20));
    float*          ct   = (float*)(wsb + ((size_t)32 << 20));
    float*          stb  = (float*)(wsb + ((size_t)33 << 20));
    float*          qkv  = (float*)(wsb + ((size_t)48 << 20));
    unsigned short* Qph  = (unsigned short*)(wsb + ((size_t)96  << 20));
    unsigned short* Qpl  = (unsigned short*)(wsb + ((size_t)104 << 20));
    unsigned short* Kph  = (unsigned short*)(wsb + ((size_t)112 << 20));
    unsigned short* Kpl  = (unsigned short*)(wsb + ((size_t)120 << 20));
    unsigned short* Vth  = (unsigned short*)(wsb + ((size_t)128 << 20));
    unsigned short* Vtl  = (unsigned short*)(wsb + ((size_t)136 << 20));
    unsigned short* hH   = (unsigned short*)(wsb + ((size_t)48 << 20));
    unsigned short* hL   = (unsigned short*)(wsb + ((size_t)80 << 20));

    // 1. xn = LN1(x)
    ln_kernel<<<NR, 256, 0, stream>>>(x, g1, be1, xbuf, actH, actL);
    // 2. qkv = xn @ Wqkv + bqkv
    wt_convert<<<dim3(TDQ / 32, DD / 32), 256, 0, stream>>>(Wqkv, wTh, wTl, DD, TDQ);
    gemm_planes<0><<<dim3(TDQ / 128, NR / 128), 256, 0, stream>>>(
        actH, actL, wTh, wTl, bqkv, nullptr, qkv, nullptr, nullptr, NR, TDQ, DD);
    // 3. RoPE + split + V transpose
    cs_table<<<(NS * HDD) / 256, 256, 0, stream>>>(sp, ct, stb);
    rope_split<<<dim3(NS / 64, NB * HH), 256, 0, stream>>>(qkv, ct, stb,
        Qph, Qpl, Kph, Kpl, Vth, Vtl);
    // 4. vals = attention -> planes
    attn_mfma<<<dim3(NS / 64, NB * HH), 256, 0, stream>>>(
        Qph, Qpl, Kph, Kpl, Vth, Vtl, pos_bias, mask, actH, actL);
    // 5. x1 = xn + vals @ Wo + bo
    wt_convert<<<dim3(DD / 32, DD / 32), 256, 0, stream>>>(Wo, wTh, wTl, DD, DD);
    gemm_planes<1><<<dim3(DD / 128, NR / 128), 256, 0, stream>>>(
        actH, actL, wTh, wTl, bo, xbuf, xbuf, nullptr, nullptr, NR, DD, DD);
    // 6. x2 = LN2(x1)
    ln_kernel<<<NR, 256, 0, stream>>>(xbuf, g2, be2, xbuf, actH, actL);
    // 7. h = gelu(x2 @ W1 + b1)
    wt_convert<<<dim3(FFF / 32, DD / 32), 256, 0, stream>>>(W1, wTh, wTl, DD, FFF);
    gemm_planes<2><<<dim3(FFF / 128, NR / 128), 256, 0, stream>>>(
        actH, actL, wTh, wTl, b1, nullptr, nullptr, hH, hL, NR, FFF, DD);
    // 8. out = x2 + h @ W2 + b2
    wt_convert<<<dim3(DD / 32, FFF / 32), 256, 0, stream>>>(W2, wTh, wTl, FFF, DD);
    gemm_planes<1><<<dim3(DD / 128, NR / 128), 256, 0, stream>>>(
        hH, hL, wTh, wTl, b2, xbuf, out, nullptr, nullptr, NR, DD, FFF);
}

// Round 4
// 711.107 us; speedup vs baseline: 4.3869x; 1.0641x over previous
//
#include <hip/hip_runtime.h>
#include <math.h>

// Problem constants (B=2, S=2048, D=1024, H=16, HD=64, FF=4096)
#define DD   1024
#define HH   16
#define HDD  64
#define FFF  4096
#define NB   2
#define NS   2048
#define NR   (NB * NS)     // 4096 rows
#define TDQ  (3 * DD)      // 3072

typedef __attribute__((ext_vector_type(8))) short bfrag;          // 8 bf16 (MFMA A/B operand)
typedef __attribute__((ext_vector_type(4))) float f32x4;          // MFMA C/D 16x16
typedef __attribute__((ext_vector_type(16))) float f32x16;        // MFMA C/D 32x32
typedef __attribute__((ext_vector_type(8))) unsigned short us8;   // 16B staging chunk
typedef __attribute__((ext_vector_type(4))) unsigned short us4;
typedef unsigned long long u64;

__device__ __forceinline__ float4 ld4(const float* p) {
    return *reinterpret_cast<const float4*>(p);
}
__device__ __forceinline__ unsigned short f2bf(float x) {   // round-to-nearest-even bf16
    unsigned int u = __float_as_uint(x);
    u += 0x7fffu + ((u >> 16) & 1u);
    return (unsigned short)(u >> 16);
}
__device__ __forceinline__ float bf2f(unsigned short h) {
    return __uint_as_float(((unsigned int)h) << 16);
}
__device__ __forceinline__ void splitbf(float x, unsigned short& hi, unsigned short& lo) {
    hi = f2bf(x);
    lo = f2bf(x - bf2f(hi));
}
__device__ __forceinline__ float gelu_f(float x) {
    return 0.5f * x * (1.0f + erff(x * 0.70710678118654752440f));
}
#define MFMA(a, b, c)   __builtin_amdgcn_mfma_f32_16x16x32_bf16((a), (b), (c), 0, 0, 0)
#define MFMA32(a, b, c) __builtin_amdgcn_mfma_f32_32x32x16_bf16((a), (b), (c), 0, 0, 0)

// ---------------- LayerNorm: fp32 out + hi/lo bf16 planes
__global__ __launch_bounds__(256) void ln_kernel(const float* __restrict__ in,
        const float* __restrict__ gw, const float* __restrict__ bw,
        float* __restrict__ outf, unsigned short* __restrict__ oh,
        unsigned short* __restrict__ ol) {
    int row = blockIdx.x;
    float4 v = reinterpret_cast<const float4*>(in + (size_t)row * DD)[threadIdx.x];
    float s1 = v.x + v.y + v.z + v.w;
    float s2 = v.x * v.x + v.y * v.y + v.z * v.z + v.w * v.w;
#pragma unroll
    for (int off = 1; off < 64; off <<= 1) {
        s1 += __shfl_xor(s1, off);
        s2 += __shfl_xor(s2, off);
    }
    __shared__ float r1[4], r2[4];
    int wid = threadIdx.x >> 6;
    if ((threadIdx.x & 63) == 0) { r1[wid] = s1; r2[wid] = s2; }
    __syncthreads();
    s1 = r1[0] + r1[1] + r1[2] + r1[3];
    s2 = r2[0] + r2[1] + r2[2] + r2[3];
    float mu   = s1 * (1.0f / DD);
    float var  = s2 * (1.0f / DD) - mu * mu;
    float rstd = rsqrtf(var + 1e-5f);
    float4 g = reinterpret_cast<const float4*>(gw)[threadIdx.x];
    float4 b = reinterpret_cast<const float4*>(bw)[threadIdx.x];
    float o[4];
    o[0] = (v.x - mu) * rstd * g.x + b.x;
    o[1] = (v.y - mu) * rstd * g.y + b.y;
    o[2] = (v.z - mu) * rstd * g.z + b.z;
    o[3] = (v.w - mu) * rstd * g.w + b.w;
    float4 of; of.x = o[0]; of.y = o[1]; of.z = o[2]; of.w = o[3];
    reinterpret_cast<float4*>(outf + (size_t)row * DD)[threadIdx.x] = of;
    us4 h4, l4;
#pragma unroll
    for (int j = 0; j < 4; ++j) { unsigned short hh, ll; splitbf(o[j], hh, ll); h4[j] = hh; l4[j] = ll; }
    *reinterpret_cast<us4*>(oh + (size_t)row * DD + threadIdx.x * 4) = h4;
    *reinterpret_cast<us4*>(ol + (size_t)row * DD + threadIdx.x * 4) = l4;
}

// ---------------- Weight transpose+split: W[K][N] fp32 -> Th/Tl[N][K] bf16
__global__ __launch_bounds__(256) void wt_convert(const float* __restrict__ W,
        unsigned short* __restrict__ Th, unsigned short* __restrict__ Tl, int K, int N) {
    __shared__ float s[32][33];
    int tx = threadIdx.x & 31, ty = threadIdx.x >> 5;   // ty 0..7
    int n0 = blockIdx.x * 32, k0 = blockIdx.y * 32;
#pragma unroll
    for (int i = 0; i < 4; ++i)
        s[ty + i * 8][tx] = W[(size_t)(k0 + ty + i * 8) * N + n0 + tx];
    __syncthreads();
#pragma unroll
    for (int i = 0; i < 4; ++i) {
        int n = n0 + ty + i * 8;
        float v = s[tx][ty + i * 8];
        unsigned short h, l; splitbf(v, h, l);
        Th[(size_t)n * K + k0 + tx] = h;
        Tl[(size_t)n * K + k0 + tx] = l;
    }
}

// ---------------- cos/sin tables for RoPE: [S][HD]
__global__ __launch_bounds__(256) void cs_table(const float* __restrict__ sp,
        float* __restrict__ ct, float* __restrict__ st) {
    int i = blockIdx.x * 256 + threadIdx.x;   // NS*HDD total
    float v = sp[i];
    ct[i] = cosf(v);
    st[i] = sinf(v);
}

// ---------------- mask int32 -> byte pre-pass (4 MB table, L3-resident)
__global__ __launch_bounds__(256) void mask8(const int* __restrict__ mask,
        unsigned char* __restrict__ mb) {
    int i = blockIdx.x * 256 + threadIdx.x;   // NS*NS/4 total
    int4 v = reinterpret_cast<const int4*>(mask)[i];
    unsigned int o = (unsigned int)(v.x & 1) | ((unsigned int)(v.y & 1) << 8)
                   | ((unsigned int)(v.z & 1) << 16) | ((unsigned int)(v.w & 1) << 24);
    reinterpret_cast<unsigned int*>(mb)[i] = o;
}

// ---------------- RoPE + split + V-transpose pre-pass.
__global__ __launch_bounds__(256) void rope_split(const float* __restrict__ qkv,
        const float* __restrict__ ct, const float* __restrict__ st,
        unsigned short* __restrict__ Qh, unsigned short* __restrict__ Ql,
        unsigned short* __restrict__ Kh, unsigned short* __restrict__ Kl,
        unsigned short* __restrict__ Vh, unsigned short* __restrict__ Vl) {
    __shared__ unsigned short svh[64][72], svl[64][72];   // transposed V tile [d][kv]
    const int t = threadIdx.x;
    const int tile = blockIdx.x, bh = blockIdx.y;
    const int b = bh >> 4, h = bh & 15;
    const int r = t >> 2;          // local row 0..63
    const int p = t & 3;
    const int srow = tile * 64 + r;
    const float* base = qkv + ((size_t)(b * NS + srow)) * TDQ + h * 192;

#pragma unroll
    for (int qk = 0; qk < 2; ++qk) {
        const float* src = base + qk * 64;
        float a[8], c[8], o1[8], o2[8];
#pragma unroll
        for (int j = 0; j < 8; ++j) {
            a[j] = src[p * 8 + j];
            c[j] = src[32 + p * 8 + j];
        }
#pragma unroll
        for (int j = 0; j < 8; ++j) {
            int d1 = p * 8 + j, d2 = 32 + p * 8 + j;
            float c1 = ct[(size_t)srow * HDD + d1], s1 = st[(size_t)srow * HDD + d1];
            float c2 = ct[(size_t)srow * HDD + d2], s2 = st[(size_t)srow * HDD + d2];
            o1[j] = a[j] * c1 - c[j] * s1;
            o2[j] = c[j] * c2 + a[j] * s2;
        }
        us8 h1, l1, h2, l2;
#pragma unroll
        for (int j = 0; j < 8; ++j) {
            unsigned short hh, ll;
            splitbf(o1[j], hh, ll); h1[j] = hh; l1[j] = ll;
            splitbf(o2[j], hh, ll); h2[j] = hh; l2[j] = ll;
        }
        unsigned short* dsth = qk ? Kh : Qh;
        unsigned short* dstl = qk ? Kl : Ql;
        size_t obase = ((size_t)bh * NS + srow) * HDD;
        *reinterpret_cast<us8*>(dsth + obase + p * 8)      = h1;
        *reinterpret_cast<us8*>(dsth + obase + 32 + p * 8) = h2;
        *reinterpret_cast<us8*>(dstl + obase + p * 8)      = l1;
        *reinterpret_cast<us8*>(dstl + obase + 32 + p * 8) = l2;
    }
    const float* vsrc = base + 128;
#pragma unroll
    for (int j = 0; j < 16; ++j) {
        unsigned short hh, ll;
        splitbf(vsrc[p * 16 + j], hh, ll);
        svh[p * 16 + j][r] = hh;
        svl[p * 16 + j][r] = ll;
    }
    __syncthreads();
    {
        int d = t >> 2, kb = (t & 3) * 16;
        size_t obase = ((size_t)bh * HDD + d) * NS + tile * 64 + kb;
        *reinterpret_cast<us8*>(Vh + obase)     = *reinterpret_cast<us8*>(&svh[d][kb]);
        *reinterpret_cast<us8*>(Vh + obase + 8) = *reinterpret_cast<us8*>(&svh[d][kb + 8]);
        *reinterpret_cast<us8*>(Vl + obase)     = *reinterpret_cast<us8*>(&svl[d][kb]);
        *reinterpret_cast<us8*>(Vl + obase + 8) = *reinterpret_cast<us8*>(&svl[d][kb + 8]);
    }
}

// ---------------- Flash attention, swapped-operand 32x32 MFMA, in-register softmax.
// Block: 4 independent waves x 32 q-rows = 128 q; K-tiles of 64.
// S^T = mfma32(K, Q): C col = lane&31 = q, row-pattern = k -> each lane owns one
// q-row with 32 k-values in registers. Softmax = in-lane + one shfl_xor(32).
// P packed bf16 hi/lo -> per-wave LDS -> A-operand of PV mfma32(P, V^T).
__global__ __launch_bounds__(256, 2) void attn_mfma(
        const unsigned short* __restrict__ Qh, const unsigned short* __restrict__ Ql,
        const unsigned short* __restrict__ Kh, const unsigned short* __restrict__ Kl,
        const unsigned short* __restrict__ Vh, const unsigned short* __restrict__ Vl,
        const float* __restrict__ pos_bias, const unsigned char* __restrict__ maskb,
        unsigned short* __restrict__ valh, unsigned short* __restrict__ vall) {
    __shared__ unsigned short kT[2][64][72];       // [plane][kv][d], swizzled
    __shared__ unsigned short vT[2][64][72];       // [plane][d][kv], swizzled
    __shared__ unsigned short pT[4][2][32][72];    // [wave][plane][q][kv], swizzled
    const int t = threadIdx.x;
    const int w = t >> 6, lane = t & 63, lq = lane & 31, hi = lane >> 5;
    const int h = blockIdx.y >> 1, b = blockIdx.y & 1;
    const int bh = b * HH + h;
    const int q0 = blockIdx.x * 128;
    const int qg = q0 + 32 * w + lq;               // this lane's q row (in-sequence)
    const int sw = ((lq >> 3) & 3) << 3;           // frag-read swizzle (shorts)
    const float C1   = 0.18033688011112042f;       // 0.125 * log2(e)
    const float NEGL = -1.0e15f;
    const float THR  = 11.5f;

    // persistent Q fragments: B-operand (col = lq = q), k-dim = d
    bfrag qf[2][4];
    {
        const unsigned short* qsrc[2] = { Qh, Ql };
#pragma unroll
        for (int pl = 0; pl < 2; ++pl)
#pragma unroll
            for (int dk = 0; dk < 4; ++dk)
                qf[pl][dk] = *reinterpret_cast<const bfrag*>(
                    qsrc[pl] + ((size_t)bh * NS + qg) * HDD + 16 * dk + 8 * hi);
    }
    f32x16 o0 = (f32x16)0.0f, o1 = (f32x16)0.0f;
    float mrun = -INFINITY, lsum = 0.0f;

    // staging: 512 16B-chunks per plane-pair; thread t handles chunk t and t+256
    const int sr0 = t >> 3, sc = t & 7;            // rows 0..31 / cols 0..7
    const int sw0 = ((sr0 >> 3) & 3) << 3;
    const int sw1 = (((sr0 + 32) >> 3) & 3) << 3;
    us8 kr[4], vr[4];

#define STAGE_LOAD(KT) {                                                          \
        int kv0_ = (KT) * 64;                                                     \
        size_t kb_ = ((size_t)bh * NS + kv0_ + sr0) * HDD + 8 * sc;               \
        size_t vb_ = ((size_t)bh * HDD + sr0) * NS + kv0_ + 8 * sc;               \
        kr[0] = *reinterpret_cast<const us8*>(Kh + kb_);                          \
        kr[1] = *reinterpret_cast<const us8*>(Kh + kb_ + (size_t)32 * HDD);       \
        kr[2] = *reinterpret_cast<const us8*>(Kl + kb_);                          \
        kr[3] = *reinterpret_cast<const us8*>(Kl + kb_ + (size_t)32 * HDD);       \
        vr[0] = *reinterpret_cast<const us8*>(Vh + vb_);                          \
        vr[1] = *reinterpret_cast<const us8*>(Vh + vb_ + (size_t)32 * NS);        \
        vr[2] = *reinterpret_cast<const us8*>(Vl + vb_);                          \
        vr[3] = *reinterpret_cast<const us8*>(Vl + vb_ + (size_t)32 * NS);        \
    }

    STAGE_LOAD(0);
    for (int kt = 0; kt < NS / 64; ++kt) {
        const int kv0 = kt * 64;
        __syncthreads();   // all waves done reading previous tile
        *reinterpret_cast<us8*>(&kT[0][sr0][(8 * sc) ^ sw0])      = kr[0];
        *reinterpret_cast<us8*>(&kT[0][32 + sr0][(8 * sc) ^ sw1]) = kr[1];
        *reinterpret_cast<us8*>(&kT[1][sr0][(8 * sc) ^ sw0])      = kr[2];
        *reinterpret_cast<us8*>(&kT[1][32 + sr0][(8 * sc) ^ sw1]) = kr[3];
        *reinterpret_cast<us8*>(&vT[0][sr0][(8 * sc) ^ sw0])      = vr[0];
        *reinterpret_cast<us8*>(&vT[0][32 + sr0][(8 * sc) ^ sw1]) = vr[1];
        *reinterpret_cast<us8*>(&vT[1][sr0][(8 * sc) ^ sw0])      = vr[2];
        *reinterpret_cast<us8*>(&vT[1][32 + sr0][(8 * sc) ^ sw1]) = vr[3];
        __syncthreads();
        if (kt + 1 < NS / 64) STAGE_LOAD(kt + 1);   // prefetch next tile

        // bias + mask direct to registers in C-layout coords:
        // lane needs (q = qg, k = kv0 + 32*m2 + 8*g + 4*hi + 0..3)
        float4 bb[8]; unsigned int mk[8];
#pragma unroll
        for (int m2 = 0; m2 < 2; ++m2)
#pragma unroll
            for (int g = 0; g < 4; ++g) {
                int i = m2 * 4 + g;
                int kc = kv0 + 32 * m2 + 8 * g + 4 * hi;
                bb[i] = ld4(pos_bias + ((size_t)h * NS + qg) * NS + kc);
                mk[i] = *reinterpret_cast<const unsigned int*>(maskb + (size_t)qg * NS + kc);
            }

        // S^T = K Q^T (3-term split), two 32-k halves
        f32x16 s0 = (f32x16)0.0f, s1 = (f32x16)0.0f;
#pragma unroll
        for (int dk = 0; dk < 4; ++dk) {
            bfrag k0h = *reinterpret_cast<const bfrag*>(&kT[0][lq][(16 * dk + 8 * hi) ^ sw]);
            bfrag k0l = *reinterpret_cast<const bfrag*>(&kT[1][lq][(16 * dk + 8 * hi) ^ sw]);
            bfrag k1h = *reinterpret_cast<const bfrag*>(&kT[0][32 + lq][(16 * dk + 8 * hi) ^ sw]);
            bfrag k1l = *reinterpret_cast<const bfrag*>(&kT[1][32 + lq][(16 * dk + 8 * hi) ^ sw]);
            s0 = MFMA32(k0h, qf[0][dk], s0);
            s0 = MFMA32(k0h, qf[1][dk], s0);
            s0 = MFMA32(k0l, qf[0][dk], s0);
            s1 = MFMA32(k1h, qf[0][dk], s1);
            s1 = MFMA32(k1h, qf[1][dk], s1);
            s1 = MFMA32(k1l, qf[0][dk], s1);
        }
        // logits (log2 domain) in registers; reg r of half m2: k = 32*m2+(r&3)+8*(r>>2)+4*hi
        float sv[2][16];
#pragma unroll
        for (int m2 = 0; m2 < 2; ++m2)
#pragma unroll
            for (int r = 0; r < 16; ++r) {
                int i = m2 * 4 + (r >> 2), c = r & 3;
                float sraw = (m2 == 0) ? s0[r] : s1[r];
                float pb = ((mk[i] >> (8 * c)) & 0xffu) ? bb[i][c] * C1 : NEGL;
                sv[m2][r] = fmaf(sraw, C1, pb);
            }
        // row max: in-lane over 32 + pair exchange
        float mx = sv[0][0];
#pragma unroll
        for (int m2 = 0; m2 < 2; ++m2)
#pragma unroll
            for (int r = 0; r < 16; ++r) mx = fmaxf(mx, sv[m2][r]);
        mx = fmaxf(mx, __shfl_xor(mx, 32));
        // defer-max rescale (rare; wave-uniform)
        if (__any(mx > mrun + THR)) {
            float mnew = fmaxf(mrun, mx);
            float corr = __builtin_amdgcn_exp2f(mrun - mnew);
            lsum *= corr;
            mrun = mnew;
#pragma unroll
            for (int r = 0; r < 16; ++r) {
                int iq = (r & 3) + 8 * (r >> 2) + 4 * hi;
                float cr = __shfl(corr, iq);
                o0[r] *= cr; o1[r] *= cr;
            }
        }
        // P = exp2(sv - m); trunc-split hi/lo, pack pairs, store to per-wave LDS
        float ps = 0.0f;
#pragma unroll
        for (int m2 = 0; m2 < 2; ++m2)
#pragma unroll
            for (int g = 0; g < 4; ++g) {
                float p0 = __builtin_amdgcn_exp2f(sv[m2][4 * g + 0] - mrun);
                float p1 = __builtin_amdgcn_exp2f(sv[m2][4 * g + 1] - mrun);
                float p2 = __builtin_amdgcn_exp2f(sv[m2][4 * g + 2] - mrun);
                float p3 = __builtin_amdgcn_exp2f(sv[m2][4 * g + 3] - mrun);
                ps += p0 + p1 + p2 + p3;
                unsigned int u0 = __float_as_uint(p0), u1 = __float_as_uint(p1);
                unsigned int u2 = __float_as_uint(p2), u3 = __float_as_uint(p3);
                float l0 = p0 - __uint_as_float(u0 & 0xffff0000u);
                float l1 = p1 - __uint_as_float(u1 & 0xffff0000u);
                float l2 = p2 - __uint_as_float(u2 & 0xffff0000u);
                float l3 = p3 - __uint_as_float(u3 & 0xffff0000u);
                unsigned int wh0 = (u0 >> 16) | (u1 & 0xffff0000u);
                unsigned int wh1 = (u2 >> 16) | (u3 & 0xffff0000u);
                unsigned int wl0 = (unsigned int)f2bf(l0) | ((unsigned int)f2bf(l1) << 16);
                unsigned int wl1 = (unsigned int)f2bf(l2) | ((unsigned int)f2bf(l3) << 16);
                int koff = (32 * m2 + 8 * g + 4 * hi) ^ sw;
                *reinterpret_cast<u64*>(&pT[w][0][lq][koff]) = (u64)wh0 | ((u64)wh1 << 32);
                *reinterpret_cast<u64*>(&pT[w][1][lq][koff]) = (u64)wl0 | ((u64)wl1 << 32);
            }
        ps += __shfl_xor(ps, 32);
        lsum += ps;
        // O += P V  (A = P rows q, B = V^T cols d)
#pragma unroll
        for (int kp = 0; kp < 4; ++kp) {
            bfrag ph = *reinterpret_cast<const bfrag*>(&pT[w][0][lq][(16 * kp + 8 * hi) ^ sw]);
            bfrag pl = *reinterpret_cast<const bfrag*>(&pT[w][1][lq][(16 * kp + 8 * hi) ^ sw]);
            bfrag v0h = *reinterpret_cast<const bfrag*>(&vT[0][lq][(16 * kp + 8 * hi) ^ sw]);
            bfrag v0l = *reinterpret_cast<const bfrag*>(&vT[1][lq][(16 * kp + 8 * hi) ^ sw]);
            bfrag v1h = *reinterpret_cast<const bfrag*>(&vT[0][32 + lq][(16 * kp + 8 * hi) ^ sw]);
            bfrag v1l = *reinterpret_cast<const bfrag*>(&vT[1][32 + lq][(16 * kp + 8 * hi) ^ sw]);
            o0 = MFMA32(ph, v0h, o0);
            o0 = MFMA32(ph, v0l, o0);
            o0 = MFMA32(pl, v0h, o0);
            o1 = MFMA32(ph, v1h, o1);
            o1 = MFMA32(ph, v1l, o1);
            o1 = MFMA32(pl, v1h, o1);
        }
    }
#undef STAGE_LOAD
    // epilogue: O[q][d] -> vals planes [b*NS+q][h*64 + d]
    float inv = 1.0f / lsum;
#pragma unroll
    for (int r = 0; r < 16; ++r) {
        int iq = (r & 3) + 8 * (r >> 2) + 4 * hi;
        float ivr = __shfl(inv, iq);
        size_t rowb = ((size_t)(b * NS + q0 + 32 * w + iq)) * DD + h * HDD;
        unsigned short hh, ll;
        splitbf(o0[r] * ivr, hh, ll);
        valh[rowb + lq] = hh;  vall[rowb + lq] = ll;
        splitbf(o1[r] * ivr, hh, ll);
        valh[rowb + 32 + lq] = hh;  vall[rowb + 32 + lq] = ll;
    }
}

// ---------------- split-bf16 MFMA GEMM (unchanged)
template<int EPI>
__global__ __launch_bounds__(256) void gemm_planes(
        const unsigned short* __restrict__ Ah, const unsigned short* __restrict__ Al,
        const unsigned short* __restrict__ Bh, const unsigned short* __restrict__ Bl,
        const float* __restrict__ bias, const float* __restrict__ resid,
        float* __restrict__ Cf, unsigned short* __restrict__ Ch, unsigned short* __restrict__ Cl,
        int M, int N, int K) {
    __shared__ unsigned short sAh[128][40], sAl[128][40];
    __shared__ unsigned short sBh[128][40], sBl[128][40];
    const int t = threadIdx.x;
    const int w = t >> 6, lane = t & 63, lq = lane & 15, lg = lane >> 4;
    const int wr = w >> 1, wc = w & 1;
    const int m0 = blockIdx.y * 128, n0 = blockIdx.x * 128;

    f32x4 acc[4][4];
#pragma unroll
    for (int m = 0; m < 4; ++m)
#pragma unroll
        for (int n = 0; n < 4; ++n) acc[m][n] = (f32x4)0.0f;

    const int sr = t >> 2;
    const int sk = (t & 3) * 8;
    const unsigned short* pAh0 = Ah + (size_t)(m0 + sr) * K + sk;
    const unsigned short* pAh1 = pAh0 + (size_t)64 * K;
    const unsigned short* pAl0 = Al + (size_t)(m0 + sr) * K + sk;
    const unsigned short* pAl1 = pAl0 + (size_t)64 * K;
    const unsigned short* pBh0 = Bh + (size_t)(n0 + sr) * K + sk;
    const unsigned short* pBh1 = pBh0 + (size_t)64 * K;
    const unsigned short* pBl0 = Bl + (size_t)(n0 + sr) * K + sk;
    const unsigned short* pBl1 = pBl0 + (size_t)64 * K;

    for (int k0 = 0; k0 < K; k0 += 32) {
        us8 a0 = *reinterpret_cast<const us8*>(pAh0 + k0);
        us8 a1 = *reinterpret_cast<const us8*>(pAh1 + k0);
        us8 a2 = *reinterpret_cast<const us8*>(pAl0 + k0);
        us8 a3 = *reinterpret_cast<const us8*>(pAl1 + k0);
        us8 b0 = *reinterpret_cast<const us8*>(pBh0 + k0);
        us8 b1 = *reinterpret_cast<const us8*>(pBh1 + k0);
        us8 b2 = *reinterpret_cast<const us8*>(pBl0 + k0);
        us8 b3 = *reinterpret_cast<const us8*>(pBl1 + k0);
        __syncthreads();
        *reinterpret_cast<us8*>(&sAh[sr][sk])      = a0;
        *reinterpret_cast<us8*>(&sAh[64 + sr][sk]) = a1;
        *reinterpret_cast<us8*>(&sAl[sr][sk])      = a2;
        *reinterpret_cast<us8*>(&sAl[64 + sr][sk]) = a3;
        *reinterpret_cast<us8*>(&sBh[sr][sk])      = b0;
        *reinterpret_cast<us8*>(&sBh[64 + sr][sk]) = b1;
        *reinterpret_cast<us8*>(&sBl[sr][sk])      = b2;
        *reinterpret_cast<us8*>(&sBl[64 + sr][sk]) = b3;
        __syncthreads();
        bfrag fah[4], fal[4], fbh[4], fbl[4];
#pragma unroll
        for (int m = 0; m < 4; ++m) {
            fah[m] = *reinterpret_cast<const bfrag*>(&sAh[wr * 64 + m * 16 + lq][lg * 8]);
            fal[m] = *reinterpret_cast<const bfrag*>(&sAl[wr * 64 + m * 16 + lq][lg * 8]);
        }
#pragma unroll
        for (int n = 0; n < 4; ++n) {
            fbh[n] = *reinterpret_cast<const bfrag*>(&sBh[wc * 64 + n * 16 + lq][lg * 8]);
            fbl[n] = *reinterpret_cast<const bfrag*>(&sBl[wc * 64 + n * 16 + lq][lg * 8]);
        }
#pragma unroll
        for (int m = 0; m < 4; ++m)
#pragma unroll
            for (int n = 0; n < 4; ++n) {
                acc[m][n] = MFMA(fah[m], fbh[n], acc[m][n]);
                acc[m][n] = MFMA(fah[m], fbl[n], acc[m][n]);
                acc[m][n] = MFMA(fal[m], fbh[n], acc[m][n]);
            }
    }
#pragma unroll
    for (int m = 0; m < 4; ++m)
#pragma unroll
        for (int r = 0; r < 4; ++r) {
            int row = m0 + wr * 64 + m * 16 + lg * 4 + r;
#pragma unroll
            for (int n = 0; n < 4; ++n) {
                int col = n0 + wc * 64 + n * 16 + lq;
                float v = acc[m][n][r] + bias[col];
                if (EPI == 1) v += resid[(size_t)row * N + col];
                if (EPI == 2) {
                    v = gelu_f(v);
                    unsigned short hh, ll; splitbf(v, hh, ll);
                    Ch[(size_t)row * N + col] = hh;
                    Cl[(size_t)row * N + col] = ll;
                } else {
                    Cf[(size_t)row * N + col] = v;
                }
            }
        }
}

extern "C" void kernel_launch(void* const* d_in, const int* in_sizes, int n_in,
                              void* d_out, int out_size, void* d_ws, size_t ws_size,
                              hipStream_t stream) {
    const float* x        = (const float*)d_in[0];
    const int*   mask     = (const int*)d_in[1];
    const float* pos_bias = (const float*)d_in[2];
    const float* sp       = (const float*)d_in[3];
    const float* Wqkv     = (const float*)d_in[4];
    const float* bqkv     = (const float*)d_in[5];
    const float* Wo       = (const float*)d_in[6];
    const float* bo       = (const float*)d_in[7];
    const float* W1       = (const float*)d_in[8];
    const float* b1       = (const float*)d_in[9];
    const float* W2       = (const float*)d_in[10];
    const float* b2       = (const float*)d_in[11];
    const float* g1       = (const float*)d_in[12];
    const float* be1      = (const float*)d_in[13];
    const float* g2       = (const float*)d_in[14];
    const float* be2      = (const float*)d_in[15];
    float* out = (float*)d_out;
    char* wsb = (char*)d_ws;

    float*          xbuf = (float*)(wsb);
    unsigned short* actH = (unsigned short*)(wsb + ((size_t)16 << 20));
    unsigned short* actL = (unsigned short*)(wsb + ((size_t)24 << 20));
    unsigned short* wTh  = (unsigned short*)(wsb + ((size_t)32 << 20));
    unsigned short* wTl  = (unsigned short*)(wsb + ((size_t)40 << 20));
    float*          ct   = (float*)(wsb + ((size_t)32 << 20));
    float*          stb  = (float*)(wsb + ((size_t)33 << 20));
    unsigned char*  mkb  = (unsigned char*)(wsb + ((size_t)34 << 20));
    float*          qkv  = (float*)(wsb + ((size_t)48 << 20));
    unsigned short* Qph  = (unsigned short*)(wsb + ((size_t)96  << 20));
    unsigned short* Qpl  = (unsigned short*)(wsb + ((size_t)104 << 20));
    unsigned short* Kph  = (unsigned short*)(wsb + ((size_t)112 << 20));
    unsigned short* Kpl  = (unsigned short*)(wsb + ((size_t)120 << 20));
    unsigned short* Vth  = (unsigned short*)(wsb + ((size_t)128 << 20));
    unsigned short* Vtl  = (unsigned short*)(wsb + ((size_t)136 << 20));
    unsigned short* hH   = (unsigned short*)(wsb + ((size_t)48 << 20));
    unsigned short* hL   = (unsigned short*)(wsb + ((size_t)80 << 20));

    // 1. xn = LN1(x)
    ln_kernel<<<NR, 256, 0, stream>>>(x, g1, be1, xbuf, actH, actL);
    // 2. qkv = xn @ Wqkv + bqkv
    wt_convert<<<dim3(TDQ / 32, DD / 32), 256, 0, stream>>>(Wqkv, wTh, wTl, DD, TDQ);
    gemm_planes<0><<<dim3(TDQ / 128, NR / 128), 256, 0, stream>>>(
        actH, actL, wTh, wTl, bqkv, nullptr, qkv, nullptr, nullptr, NR, TDQ, DD);
    // 3. tables + mask bytes + RoPE/split/V-transpose (32-48M region free after gemm1)
    cs_table<<<(NS * HDD) / 256, 256, 0, stream>>>(sp, ct, stb);
    mask8<<<(NS * NS / 4) / 256, 256, 0, stream>>>(mask, mkb);
    rope_split<<<dim3(NS / 64, NB * HH), 256, 0, stream>>>(qkv, ct, stb,
        Qph, Qpl, Kph, Kpl, Vth, Vtl);
    // 4. vals = attention -> planes
    attn_mfma<<<dim3(NS / 128, NB * HH), 256, 0, stream>>>(
        Qph, Qpl, Kph, Kpl, Vth, Vtl, pos_bias, mkb, actH, actL);
    // 5. x1 = xn + vals @ Wo + bo
    wt_convert<<<dim3(DD / 32, DD / 32), 256, 0, stream>>>(Wo, wTh, wTl, DD, DD);
    gemm_planes<1><<<dim3(DD / 128, NR / 128), 256, 0, stream>>>(
        actH, actL, wTh, wTl, bo, xbuf, xbuf, nullptr, nullptr, NR, DD, DD);
    // 6. x2 = LN2(x1)
    ln_kernel<<<NR, 256, 0, stream>>>(xbuf, g2, be2, xbuf, actH, actL);
    // 7. h = gelu(x2 @ W1 + b1)
    wt_convert<<<dim3(FFF / 32, DD / 32), 256, 0, stream>>>(W1, wTh, wTl, DD, FFF);
    gemm_planes<2><<<dim3(FFF / 128, NR / 128), 256, 0, stream>>>(
        actH, actL, wTh, wTl, b1, nullptr, nullptr, hH, hL, NR, FFF, DD);
    // 8. out = x2 + h @ W2 + b2
    wt_convert<<<dim3(DD / 32, FFF / 32), 256, 0, stream>>>(W2, wTh, wTl, FFF, DD);
    gemm_planes<1><<<dim3(DD / 128, NR / 128), 256, 0, stream>>>(
        hH, hL, wTh, wTl, b2, xbuf, out, nullptr, nullptr, NR, DD, FFF);
}

// Round 5
// 527.053 us; speedup vs baseline: 5.9188x; 1.3492x over previous
//
#include <hip/hip_runtime.h>
#include <math.h>

// Problem constants (B=2, S=2048, D=1024, H=16, HD=64, FF=4096)
#define DD   1024
#define HH   16
#define HDD  64
#define FFF  4096
#define NB   2
#define NS   2048
#define NR   (NB * NS)     // 4096 rows
#define TDQ  (3 * DD)      // 3072

typedef __attribute__((ext_vector_type(8))) _Float16 hfrag;      // 8 fp16 (MFMA A/B operand)
typedef __attribute__((ext_vector_type(4))) _Float16 h4v;        // 8B pack
typedef __attribute__((ext_vector_type(4))) float f32x4;
typedef __attribute__((ext_vector_type(16))) float f32x16;       // MFMA 32x32 C/D
typedef __attribute__((ext_vector_type(8))) unsigned short us8;  // 16B chunk

__device__ __forceinline__ float4 ld4(const float* p) {
    return *reinterpret_cast<const float4*>(p);
}
__device__ __forceinline__ float gelu_f(float x) {
    return 0.5f * x * (1.0f + erff(x * 0.70710678118654752440f));
}
#define MFMA32H(a, b, c) __builtin_amdgcn_mfma_f32_32x32x16_f16((a), (b), (c), 0, 0, 0)

// ---------------- LayerNorm: fp32 out + fp16 plane
__global__ __launch_bounds__(256) void ln_kernel(const float* __restrict__ in,
        const float* __restrict__ gw, const float* __restrict__ bw,
        float* __restrict__ outf, _Float16* __restrict__ oh) {
    int row = blockIdx.x;
    float4 v = reinterpret_cast<const float4*>(in + (size_t)row * DD)[threadIdx.x];
    float s1 = v.x + v.y + v.z + v.w;
    float s2 = v.x * v.x + v.y * v.y + v.z * v.z + v.w * v.w;
#pragma unroll
    for (int off = 1; off < 64; off <<= 1) {
        s1 += __shfl_xor(s1, off);
        s2 += __shfl_xor(s2, off);
    }
    __shared__ float r1[4], r2[4];
    int wid = threadIdx.x >> 6;
    if ((threadIdx.x & 63) == 0) { r1[wid] = s1; r2[wid] = s2; }
    __syncthreads();
    s1 = r1[0] + r1[1] + r1[2] + r1[3];
    s2 = r2[0] + r2[1] + r2[2] + r2[3];
    float mu   = s1 * (1.0f / DD);
    float var  = s2 * (1.0f / DD) - mu * mu;
    float rstd = rsqrtf(var + 1e-5f);
    float4 g = reinterpret_cast<const float4*>(gw)[threadIdx.x];
    float4 b = reinterpret_cast<const float4*>(bw)[threadIdx.x];
    float o[4];
    o[0] = (v.x - mu) * rstd * g.x + b.x;
    o[1] = (v.y - mu) * rstd * g.y + b.y;
    o[2] = (v.z - mu) * rstd * g.z + b.z;
    o[3] = (v.w - mu) * rstd * g.w + b.w;
    float4 of; of.x = o[0]; of.y = o[1]; of.z = o[2]; of.w = o[3];
    reinterpret_cast<float4*>(outf + (size_t)row * DD)[threadIdx.x] = of;
    h4v hv;
#pragma unroll
    for (int j = 0; j < 4; ++j) hv[j] = (_Float16)o[j];
    *reinterpret_cast<h4v*>(oh + (size_t)row * DD + threadIdx.x * 4) = hv;
}

// ---------------- Weight transpose: W[K][N] fp32 -> T[N][K] fp16
__global__ __launch_bounds__(256) void wt_convert(const float* __restrict__ W,
        _Float16* __restrict__ Th, int K, int N) {
    __shared__ float s[32][33];
    int tx = threadIdx.x & 31, ty = threadIdx.x >> 5;
    int n0 = blockIdx.x * 32, k0 = blockIdx.y * 32;
#pragma unroll
    for (int i = 0; i < 4; ++i)
        s[ty + i * 8][tx] = W[(size_t)(k0 + ty + i * 8) * N + n0 + tx];
    __syncthreads();
#pragma unroll
    for (int i = 0; i < 4; ++i) {
        int n = n0 + ty + i * 8;
        Th[(size_t)n * K + k0 + tx] = (_Float16)s[tx][ty + i * 8];
    }
}

// ---------------- cos/sin tables for RoPE
__global__ __launch_bounds__(256) void cs_table(const float* __restrict__ sp,
        float* __restrict__ ct, float* __restrict__ st) {
    int i = blockIdx.x * 256 + threadIdx.x;
    float v = sp[i];
    ct[i] = cosf(v);
    st[i] = sinf(v);
}

// ---------------- mask int32 -> byte
__global__ __launch_bounds__(256) void mask8(const int* __restrict__ mask,
        unsigned char* __restrict__ mb) {
    int i = blockIdx.x * 256 + threadIdx.x;
    int4 v = reinterpret_cast<const int4*>(mask)[i];
    unsigned int o = (unsigned int)(v.x & 1) | ((unsigned int)(v.y & 1) << 8)
                   | ((unsigned int)(v.z & 1) << 16) | ((unsigned int)(v.w & 1) << 24);
    reinterpret_cast<unsigned int*>(mb)[i] = o;
}

// ---------------- RoPE + V-transpose (fp16 in, fp16 out)
__global__ __launch_bounds__(256) void rope_split(const _Float16* __restrict__ qkv,
        const float* __restrict__ ct, const float* __restrict__ st,
        _Float16* __restrict__ Qp, _Float16* __restrict__ Kp, _Float16* __restrict__ Vt) {
    __shared__ _Float16 sv[64][72];
    const int t = threadIdx.x;
    const int tile = blockIdx.x, bh = blockIdx.y;
    const int b = bh >> 4, h = bh & 15;
    const int r = t >> 2, p = t & 3;
    const int srow = tile * 64 + r;
    const _Float16* base = qkv + ((size_t)(b * NS + srow)) * TDQ + h * 192;

#pragma unroll
    for (int qk = 0; qk < 2; ++qk) {
        const _Float16* src = base + qk * 64;
        hfrag va = *reinterpret_cast<const hfrag*>(src + p * 8);
        hfrag vc = *reinterpret_cast<const hfrag*>(src + 32 + p * 8);
        hfrag o1, o2;
#pragma unroll
        for (int j = 0; j < 8; ++j) {
            int d1 = p * 8 + j, d2 = 32 + p * 8 + j;
            float a = (float)va[j], c = (float)vc[j];
            float c1 = ct[(size_t)srow * HDD + d1], s1 = st[(size_t)srow * HDD + d1];
            float c2 = ct[(size_t)srow * HDD + d2], s2 = st[(size_t)srow * HDD + d2];
            o1[j] = (_Float16)(a * c1 - c * s1);
            o2[j] = (_Float16)(c * c2 + a * s2);
        }
        _Float16* dst = qk ? Kp : Qp;
        size_t obase = ((size_t)bh * NS + srow) * HDD;
        *reinterpret_cast<hfrag*>(dst + obase + p * 8)      = o1;
        *reinterpret_cast<hfrag*>(dst + obase + 32 + p * 8) = o2;
    }
    const _Float16* vsrc = base + 128;
    hfrag v0 = *reinterpret_cast<const hfrag*>(vsrc + p * 16);
    hfrag v1 = *reinterpret_cast<const hfrag*>(vsrc + p * 16 + 8);
#pragma unroll
    for (int j = 0; j < 8; ++j) {
        sv[p * 16 + j][r]     = v0[j];
        sv[p * 16 + 8 + j][r] = v1[j];
    }
    __syncthreads();
    {
        int d = t >> 2, kb = (t & 3) * 16;
        size_t obase = ((size_t)bh * HDD + d) * NS + tile * 64 + kb;
        *reinterpret_cast<hfrag*>(Vt + obase)     = *reinterpret_cast<hfrag*>(&sv[d][kb]);
        *reinterpret_cast<hfrag*>(Vt + obase + 8) = *reinterpret_cast<hfrag*>(&sv[d][kb + 8]);
    }
}

// ---------------- Flash attention, fp16 single-plane, swapped 32x32 MFMA.
__global__ __launch_bounds__(256, 3) void attn_mfma(
        const _Float16* __restrict__ Qp, const _Float16* __restrict__ Kp,
        const _Float16* __restrict__ Vt,
        const float* __restrict__ pos_bias, const unsigned char* __restrict__ maskb,
        _Float16* __restrict__ valf) {
    __shared__ _Float16 kT[64][72];       // [kv][d], swizzled
    __shared__ _Float16 vT[64][72];       // [d][kv], swizzled
    __shared__ _Float16 pT[4][32][72];    // per-wave P [q][kv], swizzled
    const int t = threadIdx.x;
    const int w = t >> 6, lane = t & 63, lq = lane & 31, hi = lane >> 5;
    const int h = blockIdx.y >> 1, b = blockIdx.y & 1;
    const int bh = b * HH + h;
    const int q0 = blockIdx.x * 128;
    const int qg = q0 + 32 * w + lq;
    const int sw = ((lq >> 3) & 3) << 3;
    const float C1   = 0.18033688011112042f;   // 0.125 * log2(e)
    const float NEGL = -1.0e15f;
    const float THR  = 11.5f;

    hfrag qf[4];
#pragma unroll
    for (int dk = 0; dk < 4; ++dk)
        qf[dk] = *reinterpret_cast<const hfrag*>(
            Qp + ((size_t)bh * NS + qg) * HDD + 16 * dk + 8 * hi);

    f32x16 o0 = (f32x16)0.0f, o1 = (f32x16)0.0f;
    float mrun = -INFINITY, lsum = 0.0f;

    const int sr0 = t >> 2, sc = t & 3;          // staging: row 0..63, col-chunk
    const int swr = ((sr0 >> 3) & 3) << 3;
    us8 kr[2], vr[2];

#define STAGE_LOAD(KT) {                                                        \
        int kv0_ = (KT) * 64;                                                   \
        size_t kb_ = ((size_t)bh * NS + kv0_ + sr0) * HDD + 16 * sc;            \
        size_t vb_ = ((size_t)bh * HDD + sr0) * NS + kv0_ + 16 * sc;            \
        kr[0] = *reinterpret_cast<const us8*>(Kp + kb_);                        \
        kr[1] = *reinterpret_cast<const us8*>(Kp + kb_ + 8);                    \
        vr[0] = *reinterpret_cast<const us8*>(Vt + vb_);                        \
        vr[1] = *reinterpret_cast<const us8*>(Vt + vb_ + 8);                    \
    }

    STAGE_LOAD(0);
    for (int kt = 0; kt < NS / 64; ++kt) {
        const int kv0 = kt * 64;
        __syncthreads();
        *reinterpret_cast<us8*>(&kT[sr0][(16 * sc) ^ swr])     = kr[0];
        *reinterpret_cast<us8*>(&kT[sr0][(16 * sc + 8) ^ swr]) = kr[1];
        *reinterpret_cast<us8*>(&vT[sr0][(16 * sc) ^ swr])     = vr[0];
        *reinterpret_cast<us8*>(&vT[sr0][(16 * sc + 8) ^ swr]) = vr[1];
        __syncthreads();
        if (kt + 1 < NS / 64) STAGE_LOAD(kt + 1);

        // bias + mask in C-layout coords
        float4 bb[8]; unsigned int mk[8];
#pragma unroll
        for (int m2 = 0; m2 < 2; ++m2)
#pragma unroll
            for (int g = 0; g < 4; ++g) {
                int i = m2 * 4 + g;
                int kc = kv0 + 32 * m2 + 8 * g + 4 * hi;
                bb[i] = ld4(pos_bias + ((size_t)h * NS + qg) * NS + kc);
                mk[i] = *reinterpret_cast<const unsigned int*>(maskb + (size_t)qg * NS + kc);
            }

        // S^T = K Q^T
        f32x16 s0 = (f32x16)0.0f, s1 = (f32x16)0.0f;
#pragma unroll
        for (int dk = 0; dk < 4; ++dk) {
            hfrag k0 = *reinterpret_cast<const hfrag*>(&kT[lq][(16 * dk + 8 * hi) ^ sw]);
            hfrag k1 = *reinterpret_cast<const hfrag*>(&kT[32 + lq][(16 * dk + 8 * hi) ^ sw]);
            s0 = MFMA32H(k0, qf[dk], s0);
            s1 = MFMA32H(k1, qf[dk], s1);
        }
        // logits (log2 domain)
        float sv[2][16];
#pragma unroll
        for (int m2 = 0; m2 < 2; ++m2)
#pragma unroll
            for (int r = 0; r < 16; ++r) {
                int i = m2 * 4 + (r >> 2), c = r & 3;
                float sraw = (m2 == 0) ? s0[r] : s1[r];
                float pb = ((mk[i] >> (8 * c)) & 0xffu) ? bb[i][c] * C1 : NEGL;
                sv[m2][r] = fmaf(sraw, C1, pb);
            }
        float mx = sv[0][0];
#pragma unroll
        for (int m2 = 0; m2 < 2; ++m2)
#pragma unroll
            for (int r = 0; r < 16; ++r) mx = fmaxf(mx, sv[m2][r]);
        mx = fmaxf(mx, __shfl_xor(mx, 32));
        if (__any(mx > mrun + THR)) {
            float mnew = fmaxf(mrun, mx);
            float corr = __builtin_amdgcn_exp2f(mrun - mnew);
            lsum *= corr;
            mrun = mnew;
#pragma unroll
            for (int r = 0; r < 16; ++r) {
                int iq = (r & 3) + 8 * (r >> 2) + 4 * hi;
                float cr = __shfl(corr, iq);
                o0[r] *= cr; o1[r] *= cr;
            }
        }
        // P = exp2(sv - m), cast fp16, store per-wave LDS
        float ps = 0.0f;
#pragma unroll
        for (int m2 = 0; m2 < 2; ++m2)
#pragma unroll
            for (int g = 0; g < 4; ++g) {
                float p0 = __builtin_amdgcn_exp2f(sv[m2][4 * g + 0] - mrun);
                float p1 = __builtin_amdgcn_exp2f(sv[m2][4 * g + 1] - mrun);
                float p2 = __builtin_amdgcn_exp2f(sv[m2][4 * g + 2] - mrun);
                float p3 = __builtin_amdgcn_exp2f(sv[m2][4 * g + 3] - mrun);
                ps += p0 + p1 + p2 + p3;
                h4v hp;
                hp[0] = (_Float16)p0; hp[1] = (_Float16)p1;
                hp[2] = (_Float16)p2; hp[3] = (_Float16)p3;
                int koff = (32 * m2 + 8 * g + 4 * hi) ^ sw;
                *reinterpret_cast<h4v*>(&pT[w][lq][koff]) = hp;
            }
        ps += __shfl_xor(ps, 32);
        lsum += ps;
        // O += P V
#pragma unroll
        for (int kp = 0; kp < 4; ++kp) {
            hfrag ph = *reinterpret_cast<const hfrag*>(&pT[w][lq][(16 * kp + 8 * hi) ^ sw]);
            hfrag v0 = *reinterpret_cast<const hfrag*>(&vT[lq][(16 * kp + 8 * hi) ^ sw]);
            hfrag v1 = *reinterpret_cast<const hfrag*>(&vT[32 + lq][(16 * kp + 8 * hi) ^ sw]);
            o0 = MFMA32H(ph, v0, o0);
            o1 = MFMA32H(ph, v1, o1);
        }
    }
#undef STAGE_LOAD
    float inv = 1.0f / lsum;
#pragma unroll
    for (int r = 0; r < 16; ++r) {
        int iq = (r & 3) + 8 * (r >> 2) + 4 * hi;
        float ivr = __shfl(inv, iq);
        size_t rowb = ((size_t)(b * NS + q0 + 32 * w + iq)) * DD + h * HDD;
        valf[rowb + lq]      = (_Float16)(o0[r] * ivr);
        valf[rowb + 32 + lq] = (_Float16)(o1[r] * ivr);
    }
}

// ---------------- fp16 MFMA GEMM: C = A[M][K] @ B[N][K]^T. 128x128 tile, BK=32,
// 4 waves x (64x64 via 2x2 32x32 frags). EPI: 0 +bias fp32; 1 +bias+resid fp32;
// 2 gelu(+bias) fp16; 3 +bias fp16.
template<int EPI>
__global__ __launch_bounds__(256, 2) void gemm_h(
        const _Float16* __restrict__ A, const _Float16* __restrict__ B,
        const float* __restrict__ bias, const float* __restrict__ resid,
        float* __restrict__ Cf, _Float16* __restrict__ Ch,
        int M, int N, int K) {
    __shared__ _Float16 sA[128][40];
    __shared__ _Float16 sB[128][40];
    const int t = threadIdx.x;
    const int w = t >> 6, lane = t & 63, lq = lane & 31, hi = lane >> 5;
    const int wr = w >> 1, wc = w & 1;
    const int m0 = blockIdx.y * 128, n0 = blockIdx.x * 128;

    f32x16 acc[2][2];
#pragma unroll
    for (int m = 0; m < 2; ++m)
#pragma unroll
        for (int n = 0; n < 2; ++n) acc[m][n] = (f32x16)0.0f;

    const int sr = t >> 1, skc = (t & 1) * 16;
    const _Float16* Ap = A + (size_t)(m0 + sr) * K + skc;
    const _Float16* Bp = B + (size_t)(n0 + sr) * K + skc;

    for (int k0 = 0; k0 < K; k0 += 32) {
        us8 a0 = *reinterpret_cast<const us8*>(Ap + k0);
        us8 a1 = *reinterpret_cast<const us8*>(Ap + k0 + 8);
        us8 b0 = *reinterpret_cast<const us8*>(Bp + k0);
        us8 b1 = *reinterpret_cast<const us8*>(Bp + k0 + 8);
        __syncthreads();
        *reinterpret_cast<us8*>(&sA[sr][skc])     = a0;
        *reinterpret_cast<us8*>(&sA[sr][skc + 8]) = a1;
        *reinterpret_cast<us8*>(&sB[sr][skc])     = b0;
        *reinterpret_cast<us8*>(&sB[sr][skc + 8]) = b1;
        __syncthreads();
        hfrag fa[2][2], fb[2][2];
#pragma unroll
        for (int mb = 0; mb < 2; ++mb)
#pragma unroll
            for (int kc = 0; kc < 2; ++kc)
                fa[mb][kc] = *reinterpret_cast<const hfrag*>(
                    &sA[wr * 64 + mb * 32 + lq][kc * 16 + 8 * hi]);
#pragma unroll
        for (int nb = 0; nb < 2; ++nb)
#pragma unroll
            for (int kc = 0; kc < 2; ++kc)
                fb[nb][kc] = *reinterpret_cast<const hfrag*>(
                    &sB[wc * 64 + nb * 32 + lq][kc * 16 + 8 * hi]);
#pragma unroll
        for (int kc = 0; kc < 2; ++kc)
#pragma unroll
            for (int mb = 0; mb < 2; ++mb)
#pragma unroll
                for (int nb = 0; nb < 2; ++nb)
                    acc[mb][nb] = MFMA32H(fa[mb][kc], fb[nb][kc], acc[mb][nb]);
    }
    // epilogue: C row = (r&3)+8*(r>>2)+4*hi, col = lq  [32x32 C layout]
#pragma unroll
    for (int mb = 0; mb < 2; ++mb)
#pragma unroll
        for (int nb = 0; nb < 2; ++nb) {
            int colg = n0 + wc * 64 + nb * 32 + lq;
            float bv = bias[colg];
#pragma unroll
            for (int r = 0; r < 16; ++r) {
                int rowg = m0 + wr * 64 + mb * 32 + (r & 3) + 8 * (r >> 2) + 4 * hi;
                float v = acc[mb][nb][r] + bv;
                if (EPI == 1) v += resid[(size_t)rowg * N + colg];
                if (EPI == 2) {
                    Ch[(size_t)rowg * N + colg] = (_Float16)gelu_f(v);
                } else if (EPI == 3) {
                    Ch[(size_t)rowg * N + colg] = (_Float16)v;
                } else {
                    Cf[(size_t)rowg * N + colg] = v;
                }
            }
        }
}

extern "C" void kernel_launch(void* const* d_in, const int* in_sizes, int n_in,
                              void* d_out, int out_size, void* d_ws, size_t ws_size,
                              hipStream_t stream) {
    const float* x        = (const float*)d_in[0];
    const int*   mask     = (const int*)d_in[1];
    const float* pos_bias = (const float*)d_in[2];
    const float* sp       = (const float*)d_in[3];
    const float* Wqkv     = (const float*)d_in[4];
    const float* bqkv     = (const float*)d_in[5];
    const float* Wo       = (const float*)d_in[6];
    const float* bo       = (const float*)d_in[7];
    const float* W1       = (const float*)d_in[8];
    const float* b1       = (const float*)d_in[9];
    const float* W2       = (const float*)d_in[10];
    const float* b2       = (const float*)d_in[11];
    const float* g1       = (const float*)d_in[12];
    const float* be1      = (const float*)d_in[13];
    const float* g2       = (const float*)d_in[14];
    const float* be2      = (const float*)d_in[15];
    float* out = (float*)d_out;
    char* wsb = (char*)d_ws;

    // ws layout (96 MB):
    //  [0,16M)   xbuf fp32 (xn -> x1 -> x2)
    //  [16,24M)  actF fp16 (xn -> vals -> x2)
    //  [24,32M)  wT fp16 (per-weight serial reuse, max 8MB)
    //  [32,33M)  ct ; [33,34M) st ; [34,38M) mask bytes
    //  [48,72M)  qkvh fp16 ; [72,80M) Qp ; [80,88M) Kp ; [88,96M) Vt
    //  hF fp16 (32MB) @48M..80M  (qkvh,Qp dead by then)
    float*          xbuf = (float*)(wsb);
    _Float16*       actF = (_Float16*)(wsb + ((size_t)16 << 20));
    _Float16*       wT   = (_Float16*)(wsb + ((size_t)24 << 20));
    float*          ct   = (float*)(wsb + ((size_t)32 << 20));
    float*          stb  = (float*)(wsb + ((size_t)33 << 20));
    unsigned char*  mkb  = (unsigned char*)(wsb + ((size_t)34 << 20));
    _Float16*       qkvh = (_Float16*)(wsb + ((size_t)48 << 20));
    _Float16*       Qp   = (_Float16*)(wsb + ((size_t)72 << 20));
    _Float16*       Kp   = (_Float16*)(wsb + ((size_t)80 << 20));
    _Float16*       Vt   = (_Float16*)(wsb + ((size_t)88 << 20));
    _Float16*       hF   = (_Float16*)(wsb + ((size_t)48 << 20));

    // 1. xn = LN1(x)
    ln_kernel<<<NR, 256, 0, stream>>>(x, g1, be1, xbuf, actF);
    // 2. qkv = xn @ Wqkv + bqkv  (fp16 out)
    wt_convert<<<dim3(TDQ / 32, DD / 32), 256, 0, stream>>>(Wqkv, wT, DD, TDQ);
    gemm_h<3><<<dim3(TDQ / 128, NR / 128), 256, 0, stream>>>(
        actF, wT, bqkv, nullptr, nullptr, qkvh, NR, TDQ, DD);
    // 3. tables + mask bytes + RoPE/V-transpose
    cs_table<<<(NS * HDD) / 256, 256, 0, stream>>>(sp, ct, stb);
    mask8<<<(NS * NS / 4) / 256, 256, 0, stream>>>(mask, mkb);
    rope_split<<<dim3(NS / 64, NB * HH), 256, 0, stream>>>(qkvh, ct, stb, Qp, Kp, Vt);
    // 4. vals = attention (fp16 into actF)
    attn_mfma<<<dim3(NS / 128, NB * HH), 256, 0, stream>>>(
        Qp, Kp, Vt, pos_bias, mkb, actF);
    // 5. x1 = xn + vals @ Wo + bo
    wt_convert<<<dim3(DD / 32, DD / 32), 256, 0, stream>>>(Wo, wT, DD, DD);
    gemm_h<1><<<dim3(DD / 128, NR / 128), 256, 0, stream>>>(
        actF, wT, bo, xbuf, xbuf, nullptr, NR, DD, DD);
    // 6. x2 = LN2(x1)
    ln_kernel<<<NR, 256, 0, stream>>>(xbuf, g2, be2, xbuf, actF);
    // 7. h = gelu(x2 @ W1 + b1) (fp16)
    wt_convert<<<dim3(FFF / 32, DD / 32), 256, 0, stream>>>(W1, wT, DD, FFF);
    gemm_h<2><<<dim3(FFF / 128, NR / 128), 256, 0, stream>>>(
        actF, wT, b1, nullptr, nullptr, hF, NR, FFF, DD);
    // 8. out = x2 + h @ W2 + b2
    wt_convert<<<dim3(DD / 32, FFF / 32), 256, 0, stream>>>(W2, wT, FFF, DD);
    gemm_h<1><<<dim3(DD / 128, NR / 128), 256, 0, stream>>>(
        hF, wT, b2, xbuf, out, nullptr, NR, DD, FFF);
}

// Round 6
// 454.307 us; speedup vs baseline: 6.8666x; 1.1601x over previous
//
#include <hip/hip_runtime.h>
#include <math.h>

// Problem constants (B=2, S=2048, D=1024, H=16, HD=64, FF=4096)
#define DD   1024
#define HH   16
#define HDD  64
#define FFF  4096
#define NB   2
#define NS   2048
#define NR   (NB * NS)     // 4096 rows
#define TDQ  (3 * DD)      // 3072

typedef __attribute__((ext_vector_type(8))) _Float16 hfrag;      // 8 fp16 (MFMA A/B operand)
typedef __attribute__((ext_vector_type(4))) _Float16 h4v;        // 8B pack
typedef __attribute__((ext_vector_type(4))) float f32x4;
typedef __attribute__((ext_vector_type(16))) float f32x16;       // MFMA 32x32 C/D
typedef __attribute__((ext_vector_type(8))) unsigned short us8;  // 16B chunk

__device__ __forceinline__ float4 ld4(const float* p) {
    return *reinterpret_cast<const float4*>(p);
}
__device__ __forceinline__ float gelu_f(float x) {
    return 0.5f * x * (1.0f + erff(x * 0.70710678118654752440f));
}
#define MFMA32H(a, b, c) __builtin_amdgcn_mfma_f32_32x32x16_f16((a), (b), (c), 0, 0, 0)

// ---------------- LayerNorm: fp32 out + fp16 plane
__global__ __launch_bounds__(256) void ln_kernel(const float* __restrict__ in,
        const float* __restrict__ gw, const float* __restrict__ bw,
        float* __restrict__ outf, _Float16* __restrict__ oh) {
    int row = blockIdx.x;
    float4 v = reinterpret_cast<const float4*>(in + (size_t)row * DD)[threadIdx.x];
    float s1 = v.x + v.y + v.z + v.w;
    float s2 = v.x * v.x + v.y * v.y + v.z * v.z + v.w * v.w;
#pragma unroll
    for (int off = 1; off < 64; off <<= 1) {
        s1 += __shfl_xor(s1, off);
        s2 += __shfl_xor(s2, off);
    }
    __shared__ float r1[4], r2[4];
    int wid = threadIdx.x >> 6;
    if ((threadIdx.x & 63) == 0) { r1[wid] = s1; r2[wid] = s2; }
    __syncthreads();
    s1 = r1[0] + r1[1] + r1[2] + r1[3];
    s2 = r2[0] + r2[1] + r2[2] + r2[3];
    float mu   = s1 * (1.0f / DD);
    float var  = s2 * (1.0f / DD) - mu * mu;
    float rstd = rsqrtf(var + 1e-5f);
    float4 g = reinterpret_cast<const float4*>(gw)[threadIdx.x];
    float4 b = reinterpret_cast<const float4*>(bw)[threadIdx.x];
    float o[4];
    o[0] = (v.x - mu) * rstd * g.x + b.x;
    o[1] = (v.y - mu) * rstd * g.y + b.y;
    o[2] = (v.z - mu) * rstd * g.z + b.z;
    o[3] = (v.w - mu) * rstd * g.w + b.w;
    float4 of; of.x = o[0]; of.y = o[1]; of.z = o[2]; of.w = o[3];
    reinterpret_cast<float4*>(outf + (size_t)row * DD)[threadIdx.x] = of;
    h4v hv;
#pragma unroll
    for (int j = 0; j < 4; ++j) hv[j] = (_Float16)o[j];
    *reinterpret_cast<h4v*>(oh + (size_t)row * DD + threadIdx.x * 4) = hv;
}

// ---------------- Weight transpose: W[K][N] fp32 -> T[N][K] fp16
__global__ __launch_bounds__(256) void wt_convert(const float* __restrict__ W,
        _Float16* __restrict__ Th, int K, int N) {
    __shared__ float s[32][33];
    int tx = threadIdx.x & 31, ty = threadIdx.x >> 5;
    int n0 = blockIdx.x * 32, k0 = blockIdx.y * 32;
#pragma unroll
    for (int i = 0; i < 4; ++i)
        s[ty + i * 8][tx] = W[(size_t)(k0 + ty + i * 8) * N + n0 + tx];
    __syncthreads();
#pragma unroll
    for (int i = 0; i < 4; ++i) {
        int n = n0 + ty + i * 8;
        Th[(size_t)n * K + k0 + tx] = (_Float16)s[tx][ty + i * 8];
    }
}

// ---------------- cos/sin tables for RoPE
__global__ __launch_bounds__(256) void cs_table(const float* __restrict__ sp,
        float* __restrict__ ct, float* __restrict__ st) {
    int i = blockIdx.x * 256 + threadIdx.x;
    float v = sp[i];
    ct[i] = cosf(v);
    st[i] = sinf(v);
}

// ---------------- mask int32 -> byte
__global__ __launch_bounds__(256) void mask8(const int* __restrict__ mask,
        unsigned char* __restrict__ mb) {
    int i = blockIdx.x * 256 + threadIdx.x;
    int4 v = reinterpret_cast<const int4*>(mask)[i];
    unsigned int o = (unsigned int)(v.x & 1) | ((unsigned int)(v.y & 1) << 8)
                   | ((unsigned int)(v.z & 1) << 16) | ((unsigned int)(v.w & 1) << 24);
    reinterpret_cast<unsigned int*>(mb)[i] = o;
}

// ---------------- RoPE + V-transpose (fp16 in, fp16 out)
__global__ __launch_bounds__(256) void rope_split(const _Float16* __restrict__ qkv,
        const float* __restrict__ ct, const float* __restrict__ st,
        _Float16* __restrict__ Qp, _Float16* __restrict__ Kp, _Float16* __restrict__ Vt) {
    __shared__ _Float16 sv[64][72];
    const int t = threadIdx.x;
    const int tile = blockIdx.x, bh = blockIdx.y;
    const int b = bh >> 4, h = bh & 15;
    const int r = t >> 2, p = t & 3;
    const int srow = tile * 64 + r;
    const _Float16* base = qkv + ((size_t)(b * NS + srow)) * TDQ + h * 192;

#pragma unroll
    for (int qk = 0; qk < 2; ++qk) {
        const _Float16* src = base + qk * 64;
        hfrag va = *reinterpret_cast<const hfrag*>(src + p * 8);
        hfrag vc = *reinterpret_cast<const hfrag*>(src + 32 + p * 8);
        hfrag o1, o2;
#pragma unroll
        for (int j = 0; j < 8; ++j) {
            int d1 = p * 8 + j, d2 = 32 + p * 8 + j;
            float a = (float)va[j], c = (float)vc[j];
            float c1 = ct[(size_t)srow * HDD + d1], s1 = st[(size_t)srow * HDD + d1];
            float c2 = ct[(size_t)srow * HDD + d2], s2 = st[(size_t)srow * HDD + d2];
            o1[j] = (_Float16)(a * c1 - c * s1);
            o2[j] = (_Float16)(c * c2 + a * s2);
        }
        _Float16* dst = qk ? Kp : Qp;
        size_t obase = ((size_t)bh * NS + srow) * HDD;
        *reinterpret_cast<hfrag*>(dst + obase + p * 8)      = o1;
        *reinterpret_cast<hfrag*>(dst + obase + 32 + p * 8) = o2;
    }
    const _Float16* vsrc = base + 128;
    hfrag v0 = *reinterpret_cast<const hfrag*>(vsrc + p * 16);
    hfrag v1 = *reinterpret_cast<const hfrag*>(vsrc + p * 16 + 8);
#pragma unroll
    for (int j = 0; j < 8; ++j) {
        sv[p * 16 + j][r]     = v0[j];
        sv[p * 16 + 8 + j][r] = v1[j];
    }
    __syncthreads();
    {
        int d = t >> 2, kb = (t & 3) * 16;
        size_t obase = ((size_t)bh * HDD + d) * NS + tile * 64 + kb;
        *reinterpret_cast<hfrag*>(Vt + obase)     = *reinterpret_cast<hfrag*>(&sv[d][kb]);
        *reinterpret_cast<hfrag*>(Vt + obase + 8) = *reinterpret_cast<hfrag*>(&sv[d][kb + 8]);
    }
}

// ---------------- Flash attention, fp16 single-plane, swapped 32x32 MFMA.
// Bias+mask staged coalesced through LDS (fp16, masked, *C1 pre-applied) in the
// same software pipeline as K/V — no scattered VMEM on the critical path.
__global__ __launch_bounds__(256) void attn_mfma(
        const _Float16* __restrict__ Qp, const _Float16* __restrict__ Kp,
        const _Float16* __restrict__ Vt,
        const float* __restrict__ pos_bias, const unsigned char* __restrict__ maskb,
        _Float16* __restrict__ valf) {
    __shared__ _Float16 kT[64][72];       // [kv][d], swizzled
    __shared__ _Float16 vT[64][72];       // [d][kv], swizzled
    __shared__ _Float16 pT[4][32][72];    // per-wave P [q][kv], swizzled
    __shared__ _Float16 PBs[4][32][68];   // per-wave masked bias (log2 dom.), stride 136B
    const int t = threadIdx.x;
    const int w = t >> 6, lane = t & 63, lq = lane & 31, hi = lane >> 5;
    const int h = blockIdx.y >> 1, b = blockIdx.y & 1;
    const int bh = b * HH + h;
    const int q0 = blockIdx.x * 128;
    const int qg = q0 + 32 * w + lq;
    const int sw = ((lq >> 3) & 3) << 3;
    const float C1  = 0.18033688011112042f;   // 0.125 * log2(e)
    const float THR = 11.5f;

    hfrag qf[4];
#pragma unroll
    for (int dk = 0; dk < 4; ++dk)
        qf[dk] = *reinterpret_cast<const hfrag*>(
            Qp + ((size_t)bh * NS + qg) * HDD + 16 * dk + 8 * hi);

    f32x16 o0 = (f32x16)0.0f, o1 = (f32x16)0.0f;
    float mrun = -INFINITY, lsum = 0.0f;

    const int sr0 = t >> 2, sc = t & 3;          // K/V staging: row 0..63, col-chunk
    const int swr = ((sr0 >> 3) & 3) << 3;
    const int brow = lane >> 4;                   // bias staging: 4 rows/iter
    const int bcol = (lane & 15) * 4;             // 16 lanes * 4 floats = full 64-col row
    us8 kr[2], vr[2];
    float4 pbr[8]; unsigned int pmk[8];

#define STAGE_LOAD(KT) {                                                        \
        int kv0_ = (KT) * 64;                                                   \
        size_t kb_ = ((size_t)bh * NS + kv0_ + sr0) * HDD + 16 * sc;            \
        size_t vb_ = ((size_t)bh * HDD + sr0) * NS + kv0_ + 16 * sc;            \
        kr[0] = *reinterpret_cast<const us8*>(Kp + kb_);                        \
        kr[1] = *reinterpret_cast<const us8*>(Kp + kb_ + 8);                    \
        vr[0] = *reinterpret_cast<const us8*>(Vt + vb_);                        \
        vr[1] = *reinterpret_cast<const us8*>(Vt + vb_ + 8);                    \
        _Pragma("unroll")                                                       \
        for (int i = 0; i < 8; ++i) {                                           \
            int rg_ = q0 + 32 * w + brow + 4 * i;                               \
            pbr[i] = ld4(pos_bias + ((size_t)h * NS + rg_) * NS + kv0_ + bcol); \
            pmk[i] = *reinterpret_cast<const unsigned int*>(                    \
                         maskb + (size_t)rg_ * NS + kv0_ + bcol);               \
        }                                                                       \
    }

    STAGE_LOAD(0);
    for (int kt = 0; kt < NS / 64; ++kt) {
        __syncthreads();
        *reinterpret_cast<us8*>(&kT[sr0][(16 * sc) ^ swr])     = kr[0];
        *reinterpret_cast<us8*>(&kT[sr0][(16 * sc + 8) ^ swr]) = kr[1];
        *reinterpret_cast<us8*>(&vT[sr0][(16 * sc) ^ swr])     = vr[0];
        *reinterpret_cast<us8*>(&vT[sr0][(16 * sc + 8) ^ swr]) = vr[1];
#pragma unroll
        for (int i = 0; i < 8; ++i) {
            h4v pv;
#pragma unroll
            for (int j = 0; j < 4; ++j)
                pv[j] = ((pmk[i] >> (8 * j)) & 0xffu)
                      ? (_Float16)(pbr[i][j] * C1) : (_Float16)(-60000.0f);
            *reinterpret_cast<h4v*>(&PBs[w][brow + 4 * i][bcol]) = pv;
        }
        __syncthreads();
        if (kt + 1 < NS / 64) STAGE_LOAD(kt + 1);

        // S^T = K Q^T
        f32x16 s0 = (f32x16)0.0f, s1 = (f32x16)0.0f;
#pragma unroll
        for (int dk = 0; dk < 4; ++dk) {
            hfrag k0 = *reinterpret_cast<const hfrag*>(&kT[lq][(16 * dk + 8 * hi) ^ sw]);
            hfrag k1 = *reinterpret_cast<const hfrag*>(&kT[32 + lq][(16 * dk + 8 * hi) ^ sw]);
            s0 = MFMA32H(k0, qf[dk], s0);
            s1 = MFMA32H(k1, qf[dk], s1);
        }
        // logits (log2 domain); bias via conflict-free LDS b64 reads
        float sv[2][16];
#pragma unroll
        for (int m2 = 0; m2 < 2; ++m2)
#pragma unroll
            for (int g = 0; g < 4; ++g) {
                h4v pb4 = *reinterpret_cast<const h4v*>(&PBs[w][lq][32 * m2 + 8 * g + 4 * hi]);
#pragma unroll
                for (int j = 0; j < 4; ++j) {
                    int r = 4 * g + j;
                    float sraw = (m2 == 0) ? s0[r] : s1[r];
                    sv[m2][r] = fmaf(sraw, C1, (float)pb4[j]);
                }
            }
        float mx = sv[0][0];
#pragma unroll
        for (int m2 = 0; m2 < 2; ++m2)
#pragma unroll
            for (int r = 0; r < 16; ++r) mx = fmaxf(mx, sv[m2][r]);
        mx = fmaxf(mx, __shfl_xor(mx, 32));
        if (__any(mx > mrun + THR)) {
            float mnew = fmaxf(mrun, mx);
            float corr = __builtin_amdgcn_exp2f(mrun - mnew);
            lsum *= corr;
            mrun = mnew;
#pragma unroll
            for (int r = 0; r < 16; ++r) {
                int iq = (r & 3) + 8 * (r >> 2) + 4 * hi;
                float cr = __shfl(corr, iq);
                o0[r] *= cr; o1[r] *= cr;
            }
        }
        // P = exp2(sv - m), cast fp16, store per-wave LDS
        float ps = 0.0f;
#pragma unroll
        for (int m2 = 0; m2 < 2; ++m2)
#pragma unroll
            for (int g = 0; g < 4; ++g) {
                float p0 = __builtin_amdgcn_exp2f(sv[m2][4 * g + 0] - mrun);
                float p1 = __builtin_amdgcn_exp2f(sv[m2][4 * g + 1] - mrun);
                float p2 = __builtin_amdgcn_exp2f(sv[m2][4 * g + 2] - mrun);
                float p3 = __builtin_amdgcn_exp2f(sv[m2][4 * g + 3] - mrun);
                ps += p0 + p1 + p2 + p3;
                h4v hp;
                hp[0] = (_Float16)p0; hp[1] = (_Float16)p1;
                hp[2] = (_Float16)p2; hp[3] = (_Float16)p3;
                int koff = (32 * m2 + 8 * g + 4 * hi) ^ sw;
                *reinterpret_cast<h4v*>(&pT[w][lq][koff]) = hp;
            }
        ps += __shfl_xor(ps, 32);
        lsum += ps;
        // O += P V
#pragma unroll
        for (int kp = 0; kp < 4; ++kp) {
            hfrag ph = *reinterpret_cast<const hfrag*>(&pT[w][lq][(16 * kp + 8 * hi) ^ sw]);
            hfrag v0 = *reinterpret_cast<const hfrag*>(&vT[lq][(16 * kp + 8 * hi) ^ sw]);
            hfrag v1 = *reinterpret_cast<const hfrag*>(&vT[32 + lq][(16 * kp + 8 * hi) ^ sw]);
            o0 = MFMA32H(ph, v0, o0);
            o1 = MFMA32H(ph, v1, o1);
        }
    }
#undef STAGE_LOAD
    float inv = 1.0f / lsum;
#pragma unroll
    for (int r = 0; r < 16; ++r) {
        int iq = (r & 3) + 8 * (r >> 2) + 4 * hi;
        float ivr = __shfl(inv, iq);
        size_t rowb = ((size_t)(b * NS + q0 + 32 * w + iq)) * DD + h * HDD;
        valf[rowb + lq]      = (_Float16)(o0[r] * ivr);
        valf[rowb + 32 + lq] = (_Float16)(o1[r] * ivr);
    }
}

// ---------------- fp16 MFMA GEMM (unchanged from round 5)
template<int EPI>
__global__ __launch_bounds__(256, 2) void gemm_h(
        const _Float16* __restrict__ A, const _Float16* __restrict__ B,
        const float* __restrict__ bias, const float* __restrict__ resid,
        float* __restrict__ Cf, _Float16* __restrict__ Ch,
        int M, int N, int K) {
    __shared__ _Float16 sA[128][40];
    __shared__ _Float16 sB[128][40];
    const int t = threadIdx.x;
    const int w = t >> 6, lane = t & 63, lq = lane & 31, hi = lane >> 5;
    const int wr = w >> 1, wc = w & 1;
    const int m0 = blockIdx.y * 128, n0 = blockIdx.x * 128;

    f32x16 acc[2][2];
#pragma unroll
    for (int m = 0; m < 2; ++m)
#pragma unroll
        for (int n = 0; n < 2; ++n) acc[m][n] = (f32x16)0.0f;

    const int sr = t >> 1, skc = (t & 1) * 16;
    const _Float16* Ap = A + (size_t)(m0 + sr) * K + skc;
    const _Float16* Bp = B + (size_t)(n0 + sr) * K + skc;

    for (int k0 = 0; k0 < K; k0 += 32) {
        us8 a0 = *reinterpret_cast<const us8*>(Ap + k0);
        us8 a1 = *reinterpret_cast<const us8*>(Ap + k0 + 8);
        us8 b0 = *reinterpret_cast<const us8*>(Bp + k0);
        us8 b1 = *reinterpret_cast<const us8*>(Bp + k0 + 8);
        __syncthreads();
        *reinterpret_cast<us8*>(&sA[sr][skc])     = a0;
        *reinterpret_cast<us8*>(&sA[sr][skc + 8]) = a1;
        *reinterpret_cast<us8*>(&sB[sr][skc])     = b0;
        *reinterpret_cast<us8*>(&sB[sr][skc + 8]) = b1;
        __syncthreads();
        hfrag fa[2][2], fb[2][2];
#pragma unroll
        for (int mb = 0; mb < 2; ++mb)
#pragma unroll
            for (int kc = 0; kc < 2; ++kc)
                fa[mb][kc] = *reinterpret_cast<const hfrag*>(
                    &sA[wr * 64 + mb * 32 + lq][kc * 16 + 8 * hi]);
#pragma unroll
        for (int nb = 0; nb < 2; ++nb)
#pragma unroll
            for (int kc = 0; kc < 2; ++kc)
                fb[nb][kc] = *reinterpret_cast<const hfrag*>(
                    &sB[wc * 64 + nb * 32 + lq][kc * 16 + 8 * hi]);
#pragma unroll
        for (int kc = 0; kc < 2; ++kc)
#pragma unroll
            for (int mb = 0; mb < 2; ++mb)
#pragma unroll
                for (int nb = 0; nb < 2; ++nb)
                    acc[mb][nb] = MFMA32H(fa[mb][kc], fb[nb][kc], acc[mb][nb]);
    }
#pragma unroll
    for (int mb = 0; mb < 2; ++mb)
#pragma unroll
        for (int nb = 0; nb < 2; ++nb) {
            int colg = n0 + wc * 64 + nb * 32 + lq;
            float bv = bias[colg];
#pragma unroll
            for (int r = 0; r < 16; ++r) {
                int rowg = m0 + wr * 64 + mb * 32 + (r & 3) + 8 * (r >> 2) + 4 * hi;
                float v = acc[mb][nb][r] + bv;
                if (EPI == 1) v += resid[(size_t)rowg * N + colg];
                if (EPI == 2) {
                    Ch[(size_t)rowg * N + colg] = (_Float16)gelu_f(v);
                } else if (EPI == 3) {
                    Ch[(size_t)rowg * N + colg] = (_Float16)v;
                } else {
                    Cf[(size_t)rowg * N + colg] = v;
                }
            }
        }
}

extern "C" void kernel_launch(void* const* d_in, const int* in_sizes, int n_in,
                              void* d_out, int out_size, void* d_ws, size_t ws_size,
                              hipStream_t stream) {
    const float* x        = (const float*)d_in[0];
    const int*   mask     = (const int*)d_in[1];
    const float* pos_bias = (const float*)d_in[2];
    const float* sp       = (const float*)d_in[3];
    const float* Wqkv     = (const float*)d_in[4];
    const float* bqkv     = (const float*)d_in[5];
    const float* Wo       = (const float*)d_in[6];
    const float* bo       = (const float*)d_in[7];
    const float* W1       = (const float*)d_in[8];
    const float* b1       = (const float*)d_in[9];
    const float* W2       = (const float*)d_in[10];
    const float* b2       = (const float*)d_in[11];
    const float* g1       = (const float*)d_in[12];
    const float* be1      = (const float*)d_in[13];
    const float* g2       = (const float*)d_in[14];
    const float* be2      = (const float*)d_in[15];
    float* out = (float*)d_out;
    char* wsb = (char*)d_ws;

    float*          xbuf = (float*)(wsb);
    _Float16*       actF = (_Float16*)(wsb + ((size_t)16 << 20));
    _Float16*       wT   = (_Float16*)(wsb + ((size_t)24 << 20));
    float*          ct   = (float*)(wsb + ((size_t)32 << 20));
    float*          stb  = (float*)(wsb + ((size_t)33 << 20));
    unsigned char*  mkb  = (unsigned char*)(wsb + ((size_t)34 << 20));
    _Float16*       qkvh = (_Float16*)(wsb + ((size_t)48 << 20));
    _Float16*       Qp   = (_Float16*)(wsb + ((size_t)72 << 20));
    _Float16*       Kp   = (_Float16*)(wsb + ((size_t)80 << 20));
    _Float16*       Vt   = (_Float16*)(wsb + ((size_t)88 << 20));
    _Float16*       hF   = (_Float16*)(wsb + ((size_t)48 << 20));

    // 1. xn = LN1(x)
    ln_kernel<<<NR, 256, 0, stream>>>(x, g1, be1, xbuf, actF);
    // 2. qkv = xn @ Wqkv + bqkv  (fp16 out)
    wt_convert<<<dim3(TDQ / 32, DD / 32), 256, 0, stream>>>(Wqkv, wT, DD, TDQ);
    gemm_h<3><<<dim3(TDQ / 128, NR / 128), 256, 0, stream>>>(
        actF, wT, bqkv, nullptr, nullptr, qkvh, NR, TDQ, DD);
    // 3. tables + mask bytes + RoPE/V-transpose
    cs_table<<<(NS * HDD) / 256, 256, 0, stream>>>(sp, ct, stb);
    mask8<<<(NS * NS / 4) / 256, 256, 0, stream>>>(mask, mkb);
    rope_split<<<dim3(NS / 64, NB * HH), 256, 0, stream>>>(qkvh, ct, stb, Qp, Kp, Vt);
    // 4. vals = attention (fp16 into actF)
    attn_mfma<<<dim3(NS / 128, NB * HH), 256, 0, stream>>>(
        Qp, Kp, Vt, pos_bias, mkb, actF);
    // 5. x1 = xn + vals @ Wo + bo
    wt_convert<<<dim3(DD / 32, DD / 32), 256, 0, stream>>>(Wo, wT, DD, DD);
    gemm_h<1><<<dim3(DD / 128, NR / 128), 256, 0, stream>>>(
        actF, wT, bo, xbuf, xbuf, nullptr, NR, DD, DD);
    // 6. x2 = LN2(x1)
    ln_kernel<<<NR, 256, 0, stream>>>(xbuf, g2, be2, xbuf, actF);
    // 7. h = gelu(x2 @ W1 + b1) (fp16)
    wt_convert<<<dim3(FFF / 32, DD / 32), 256, 0, stream>>>(W1, wT, DD, FFF);
    gemm_h<2><<<dim3(FFF / 128, NR / 128), 256, 0, stream>>>(
        actF, wT, b1, nullptr, nullptr, hF, NR, FFF, DD);
    // 8. out = x2 + h @ W2 + b2
    wt_convert<<<dim3(DD / 32, FFF / 32), 256, 0, stream>>>(W2, wT, FFF, DD);
    gemm_h<1><<<dim3(DD / 128, NR / 128), 256, 0, stream>>>(
        hF, wT, b2, xbuf, out, nullptr, NR, DD, FFF);
}